// Round 1
// baseline (3496.766 us; speedup 1.0000x reference)
//
#include <hip/hip_runtime.h>
#include <hip/hip_bf16.h>

// ---------------------------------------------------------------------------
// GraphTransformer: 3x TransformerConv(H=8,c=16) + BN/ReLU, fixed graph.
// CSR-by-dst build once; per layer: node GEMMs, edge GEMM (bf16 store),
// wave-per-node segment-softmax aggregation, BN+ReLU.
// ---------------------------------------------------------------------------

// ---------------- CSR build ----------------
__global__ void hist_kernel(const int* __restrict__ dst, int E, int* __restrict__ hist) {
    int i = blockIdx.x * blockDim.x + threadIdx.x;
    if (i < E) atomicAdd(&hist[dst[i]], 1);
}

__global__ __launch_bounds__(1024) void scan_kernel(const int* __restrict__ hist, int n, int total,
                                                    int* __restrict__ row_ptr, int* __restrict__ cursor) {
    __shared__ int lds[1024];
    __shared__ int s_running;
    int tid = threadIdx.x;
    if (tid == 0) s_running = 0;
    __syncthreads();
    for (int base = 0; base < n; base += 1024) {
        int i = base + tid;
        int vv = (i < n) ? hist[i] : 0;
        lds[tid] = vv;
        __syncthreads();
        for (int off = 1; off < 1024; off <<= 1) {
            int t = (tid >= off) ? lds[tid - off] : 0;
            __syncthreads();
            lds[tid] += t;
            __syncthreads();
        }
        int excl = lds[tid] - vv;
        int run = s_running;
        if (i < n) { row_ptr[i] = run + excl; cursor[i] = run + excl; }
        __syncthreads();
        if (tid == 0) s_running = run + lds[1023];
        __syncthreads();
    }
    if (tid == 0) row_ptr[n] = total;
}

__global__ void scatter_kernel(const int* __restrict__ src, const int* __restrict__ dst, int E,
                               int* __restrict__ cursor, int* __restrict__ eid, int* __restrict__ srcs) {
    int i = blockIdx.x * blockDim.x + threadIdx.x;
    if (i < E) {
        int d = dst[i];
        int pos = atomicAdd(&cursor[d], 1);
        eid[pos] = i;
        srcs[pos] = src[i];
    }
}

// ---------------- node GEMMs: q,k,v,skip ----------------
template <int DI>
__global__ __launch_bounds__(128) void node_gemm_kernel(
    const float* __restrict__ hin, int N,
    const float* __restrict__ Wq, const float* __restrict__ bq,
    const float* __restrict__ Wk, const float* __restrict__ bk,
    const float* __restrict__ Wv, const float* __restrict__ bv,
    const float* __restrict__ Ws, const float* __restrict__ bs,
    float* __restrict__ q, float* __restrict__ k, float* __restrict__ v,
    float* __restrict__ skipout)
{
    const int NB = 16;
    __shared__ float hl[NB][DI];
    int n0 = blockIdx.x * NB;
    int tid = threadIdx.x;  // 128
    for (int idx = tid; idx < NB * DI; idx += 128) {
        int nd = idx / DI, kk = idx % DI;
        int n = n0 + nd;
        hl[nd][kk] = (n < N) ? hin[(size_t)n * DI + kk] : 0.0f;
    }
    __syncthreads();
    const float* Wmat[4] = {Wq, Wk, Wv, Ws};
    const float* bias[4] = {bq, bk, bv, bs};
    float* outs[4] = {q, k, v, skipout};
    int c = tid;
#pragma unroll
    for (int w = 0; w < 4; ++w) {
        const float* W = Wmat[w];
        float acc[NB];
#pragma unroll
        for (int nd = 0; nd < NB; nd++) acc[nd] = 0.f;
        for (int k0 = 0; k0 < DI; k0 += 16) {
            float wr[16];
#pragma unroll
            for (int kk = 0; kk < 16; kk++) wr[kk] = W[(k0 + kk) * 128 + c];
#pragma unroll
            for (int nd = 0; nd < NB; nd++) {
#pragma unroll
                for (int kk = 0; kk < 16; kk++)
                    acc[nd] += hl[nd][k0 + kk] * wr[kk];
            }
        }
        float b = bias[w][c];
        for (int nd = 0; nd < NB; nd++) {
            int n = n0 + nd;
            if (n < N) outs[w][(size_t)n * 128 + c] = acc[nd] + b;
        }
    }
}

// ---------------- edge GEMM: e = edge_attr[eid] @ We, bf16 store ----------------
__global__ __launch_bounds__(128) void e_gemm_kernel(
    const float* __restrict__ edge_attr, const int* __restrict__ eid, int E,
    const float* __restrict__ We, __hip_bfloat16* __restrict__ e_out)
{
    const int EB = 32;
    __shared__ float Wl[64 * 128];   // 32KB
    __shared__ float al[EB][64];     // 8KB
    int tid = threadIdx.x;  // 128
    for (int idx = tid; idx < 64 * 128; idx += 128) Wl[idx] = We[idx];
    int j0 = blockIdx.x * EB;
    for (int idx = tid; idx < EB * 64; idx += 128) {
        int es = idx / 64, kk = idx % 64;
        int j = j0 + es;
        float vv = 0.f;
        if (j < E) { int r = eid[j]; vv = edge_attr[(size_t)r * 64 + kk]; }
        al[es][kk] = vv;
    }
    __syncthreads();
    int c = tid;
    float acc[EB];
#pragma unroll
    for (int es = 0; es < EB; es++) acc[es] = 0.f;
    for (int k0 = 0; k0 < 64; k0 += 8) {
        float wr[8];
#pragma unroll
        for (int kk = 0; kk < 8; kk++) wr[kk] = Wl[(k0 + kk) * 128 + c];
#pragma unroll
        for (int es = 0; es < EB; es++) {
#pragma unroll
            for (int kk = 0; kk < 8; kk++)
                acc[es] += al[es][k0 + kk] * wr[kk];
        }
    }
    for (int es = 0; es < EB; es++) {
        int j = j0 + es;
        if (j < E) e_out[(size_t)j * 128 + c] = __float2bfloat16(acc[es]);
    }
}

// ---------------- aggregation: segment softmax + message sum + skip ----------------
__global__ __launch_bounds__(256) void agg_kernel(
    const int* __restrict__ row_ptr, const int* __restrict__ srcs,
    const float* __restrict__ q, const float* __restrict__ k,
    const float* __restrict__ v, const __hip_bfloat16* __restrict__ e,
    float* __restrict__ hout, int N)
{
    int wave = threadIdx.x >> 6;
    int lane = threadIdx.x & 63;
    int n = blockIdx.x * 4 + wave;
    if (n >= N) return;

    const float2* q2 = (const float2*)q;
    const float2* k2 = (const float2*)k;
    const float2* v2 = (const float2*)v;
    const unsigned int* e32 = (const unsigned int*)e;
    float2* h2 = (float2*)hout;

    float2 qq = q2[(size_t)n * 64 + lane];
    float2 sk = h2[(size_t)n * 64 + lane];
    float acc0 = 0.f, acc1 = 0.f, sw = 0.f;
    int jb = row_ptr[n], je = row_ptr[n + 1];
    for (int j = jb; j < je; ++j) {
        int s = srcs[j];
        unsigned int ee = e32[(size_t)j * 64 + lane];
        float e0 = __uint_as_float(ee << 16);
        float e1 = __uint_as_float(ee & 0xffff0000u);
        float2 kk = k2[(size_t)s * 64 + lane];
        float2 vv = v2[(size_t)s * 64 + lane];
        float part = qq.x * (kk.x + e0) + qq.y * (kk.y + e1);
        part += __shfl_xor(part, 1);
        part += __shfl_xor(part, 2);
        part += __shfl_xor(part, 4);
        float w = __expf(part * 0.25f);   // 1/sqrt(16)
        acc0 += w * (vv.x + e0);
        acc1 += w * (vv.y + e1);
        sw += w;
    }
    float inv = 1.0f / (sw + 1e-16f);
    float2 o;
    o.x = acc0 * inv + sk.x;
    o.y = acc1 * inv + sk.y;
    h2[(size_t)n * 64 + lane] = o;
}

// ---------------- BatchNorm + ReLU ----------------
__global__ __launch_bounds__(128) void bn_stats_kernel(const float* __restrict__ h, int N,
                                                       float* __restrict__ sums) {
    int f = threadIdx.x;  // 128
    float s = 0.f, s2 = 0.f;
    for (int n = blockIdx.x; n < N; n += gridDim.x) {
        float x = h[(size_t)n * 128 + f];
        s += x;
        s2 += x * x;
    }
    atomicAdd(&sums[f], s);
    atomicAdd(&sums[128 + f], s2);
}

__global__ __launch_bounds__(256) void bn_apply_kernel(
    const float* __restrict__ h, const float* __restrict__ sums,
    const float* __restrict__ g, const float* __restrict__ be,
    float* __restrict__ out, int N)
{
    int idx = blockIdx.x * blockDim.x + threadIdx.x;
    if (idx >= N * 128) return;
    int f = idx & 127;
    float invN = 1.0f / (float)N;
    float mu = sums[f] * invN;
    float var = sums[128 + f] * invN - mu * mu;
    float x = (h[idx] - mu) * rsqrtf(var + 1e-5f) * g[f] + be[f];
    out[idx] = fmaxf(x, 0.f);
}

// ---------------------------------------------------------------------------
extern "C" void kernel_launch(void* const* d_in, const int* in_sizes, int n_in,
                              void* d_out, int out_size, void* d_ws, size_t ws_size,
                              hipStream_t stream)
{
    const float* x = (const float*)d_in[0];
    const int* edge_index = (const int*)d_in[1];
    const float* edge_attr = (const float*)d_in[2];
    int N = in_sizes[0] / 64;
    int E = in_sizes[1] / 2;
    const int* src = edge_index;
    const int* dst = edge_index + E;

    const float* W[3][9];
    for (int l = 0; l < 3; l++)
        for (int i = 0; i < 9; i++) W[l][i] = (const float*)d_in[3 + l * 9 + i];
    // W indices: 0:Wq 1:bq 2:Wk 3:bk 4:Wv 5:bv 6:We 7:Ws 8:bs
    const float* g0 = (const float*)d_in[30];
    const float* be0 = (const float*)d_in[31];
    const float* g1 = (const float*)d_in[32];
    const float* be1 = (const float*)d_in[33];

    char* p = (char*)d_ws;
    auto alloc = [&](size_t bytes) -> char* {
        char* r = p;
        p += (bytes + 255) & ~(size_t)255;
        return r;
    };
    float* q = (float*)alloc((size_t)N * 128 * 4);
    float* k = (float*)alloc((size_t)N * 128 * 4);
    float* v = (float*)alloc((size_t)N * 128 * 4);
    float* A = (float*)alloc((size_t)N * 128 * 4);
    float* B = (float*)alloc((size_t)N * 128 * 4);
    __hip_bfloat16* e = (__hip_bfloat16*)alloc((size_t)E * 128 * 2);
    int* row_ptr = (int*)alloc((size_t)(N + 1) * 4);
    int* cursor = (int*)alloc((size_t)N * 4);
    int* histb = (int*)alloc((size_t)N * 4);
    int* eid = (int*)alloc((size_t)E * 4);
    int* srcs = (int*)alloc((size_t)E * 4);
    float* sums = (float*)alloc(256 * 4);

    // ---- CSR build (per call; graph is fixed input) ----
    hipMemsetAsync(histb, 0, (size_t)N * 4, stream);
    hist_kernel<<<(E + 255) / 256, 256, 0, stream>>>(dst, E, histb);
    scan_kernel<<<1, 1024, 0, stream>>>(histb, N, E, row_ptr, cursor);
    scatter_kernel<<<(E + 255) / 256, 256, 0, stream>>>(src, dst, E, cursor, eid, srcs);

    for (int l = 0; l < 3; l++) {
        const float* hin = (l == 0) ? x : A;
        float* skipbuf = (l == 2) ? (float*)d_out : B;
        if (l == 0)
            node_gemm_kernel<64><<<(N + 15) / 16, 128, 0, stream>>>(
                hin, N, W[l][0], W[l][1], W[l][2], W[l][3], W[l][4], W[l][5], W[l][7], W[l][8],
                q, k, v, skipbuf);
        else
            node_gemm_kernel<128><<<(N + 15) / 16, 128, 0, stream>>>(
                hin, N, W[l][0], W[l][1], W[l][2], W[l][3], W[l][4], W[l][5], W[l][7], W[l][8],
                q, k, v, skipbuf);
        e_gemm_kernel<<<(E + 31) / 32, 128, 0, stream>>>(edge_attr, eid, E, W[l][6], e);
        agg_kernel<<<(N + 3) / 4, 256, 0, stream>>>(row_ptr, srcs, q, k, v, e, skipbuf, N);
        if (l < 2) {
            hipMemsetAsync(sums, 0, 256 * 4, stream);
            bn_stats_kernel<<<256, 128, 0, stream>>>(skipbuf, N, sums);
            const float* gg = (l == 0) ? g0 : g1;
            const float* bb = (l == 0) ? be0 : be1;
            bn_apply_kernel<<<((size_t)N * 128 + 255) / 256, 256, 0, stream>>>(skipbuf, sums, gg, bb, A, N);
        }
    }

    // ---- second output: edge_attr passthrough ----
    hipMemcpyAsync((float*)d_out + (size_t)N * 128, edge_attr, (size_t)E * 64 * 4,
                   hipMemcpyDeviceToDevice, stream);
}

// Round 2
// 1714.328 us; speedup vs baseline: 2.0397x; 2.0397x over previous
//
#include <hip/hip_runtime.h>
#include <hip/hip_bf16.h>

typedef __attribute__((ext_vector_type(8))) short short8;
typedef __attribute__((ext_vector_type(4))) float f32x4;
typedef unsigned short ushort_t;

static __device__ __forceinline__ ushort_t f2bf(float x) {
    __hip_bfloat16 h = __float2bfloat16(x);
    return *(ushort_t*)&h;
}

// ---------------------------------------------------------------------------
// GraphTransformer: 3x TransformerConv(H=8,c=16) + BN/ReLU, fixed graph.
// CSR-by-dst build once; per layer: node GEMMs (fp32 VALU), edge GEMM (MFMA
// bf16), wave-per-node segment-softmax aggregation, BN+ReLU.
// ---------------------------------------------------------------------------

// ---------------- CSR build ----------------
__global__ void hist_kernel(const int* __restrict__ dst, int E, int* __restrict__ hist) {
    int i = blockIdx.x * blockDim.x + threadIdx.x;
    if (i < E) atomicAdd(&hist[dst[i]], 1);
}

__global__ __launch_bounds__(1024) void scan_kernel(const int* __restrict__ hist, int n, int total,
                                                    int* __restrict__ row_ptr, int* __restrict__ cursor) {
    __shared__ int lds[1024];
    __shared__ int s_running;
    int tid = threadIdx.x;
    if (tid == 0) s_running = 0;
    __syncthreads();
    for (int base = 0; base < n; base += 1024) {
        int i = base + tid;
        int vv = (i < n) ? hist[i] : 0;
        lds[tid] = vv;
        __syncthreads();
        for (int off = 1; off < 1024; off <<= 1) {
            int t = (tid >= off) ? lds[tid - off] : 0;
            __syncthreads();
            lds[tid] += t;
            __syncthreads();
        }
        int excl = lds[tid] - vv;
        int run = s_running;
        if (i < n) { row_ptr[i] = run + excl; cursor[i] = run + excl; }
        __syncthreads();
        if (tid == 0) s_running = run + lds[1023];
        __syncthreads();
    }
    if (tid == 0) row_ptr[n] = total;
}

__global__ void scatter_kernel(const int* __restrict__ src, const int* __restrict__ dst, int E,
                               int* __restrict__ cursor, int* __restrict__ eid, int* __restrict__ srcs) {
    int i = blockIdx.x * blockDim.x + threadIdx.x;
    if (i < E) {
        int d = dst[i];
        int pos = atomicAdd(&cursor[d], 1);
        eid[pos] = i;
        srcs[pos] = src[i];
    }
}

// ---------------- node GEMMs: q,k,v,skip (fp32 VALU) ----------------
template <int DI>
__global__ __launch_bounds__(128) void node_gemm_kernel(
    const float* __restrict__ hin, int N,
    const float* __restrict__ Wq, const float* __restrict__ bq,
    const float* __restrict__ Wk, const float* __restrict__ bk,
    const float* __restrict__ Wv, const float* __restrict__ bv,
    const float* __restrict__ Ws, const float* __restrict__ bs,
    float* __restrict__ q, float* __restrict__ k, float* __restrict__ v,
    float* __restrict__ skipout)
{
    const int NB = 16;
    __shared__ float hl[NB][DI];
    int n0 = blockIdx.x * NB;
    int tid = threadIdx.x;  // 128
    for (int idx = tid; idx < NB * DI; idx += 128) {
        int nd = idx / DI, kk = idx % DI;
        int n = n0 + nd;
        hl[nd][kk] = (n < N) ? hin[(size_t)n * DI + kk] : 0.0f;
    }
    __syncthreads();
    const float* Wmat[4] = {Wq, Wk, Wv, Ws};
    const float* bias[4] = {bq, bk, bv, bs};
    float* outs[4] = {q, k, v, skipout};
    int c = tid;
#pragma unroll
    for (int w = 0; w < 4; ++w) {
        const float* W = Wmat[w];
        float acc[NB];
#pragma unroll
        for (int nd = 0; nd < NB; nd++) acc[nd] = 0.f;
        for (int k0 = 0; k0 < DI; k0 += 16) {
            float wr[16];
#pragma unroll
            for (int kk = 0; kk < 16; kk++) wr[kk] = W[(k0 + kk) * 128 + c];
#pragma unroll
            for (int nd = 0; nd < NB; nd++) {
#pragma unroll
                for (int kk = 0; kk < 16; kk++)
                    acc[nd] += hl[nd][k0 + kk] * wr[kk];
            }
        }
        float b = bias[w][c];
        for (int nd = 0; nd < NB; nd++) {
            int n = n0 + nd;
            if (n < N) outs[w][(size_t)n * 128 + c] = acc[nd] + b;
        }
    }
}

// ---------------- pack We into MFMA B-fragment layout ----------------
// Bpack[layer][t][kk][lane][j] = bf16( We_layer[kk*32 + (lane>>4)*8 + j][t*16 + (lane&15)] )
__global__ __launch_bounds__(256) void pack_We_kernel(
    const float* __restrict__ We0, const float* __restrict__ We1,
    const float* __restrict__ We2, ushort_t* __restrict__ Bpack)
{
    int idx = blockIdx.x * blockDim.x + threadIdx.x;
    if (idx >= 3 * 8192) return;
    int j = idx & 7;
    int lane = (idx >> 3) & 63;
    int kk = (idx >> 9) & 1;
    int t = (idx >> 10) & 7;
    int layer = idx >> 13;
    const float* We = (layer == 0) ? We0 : (layer == 1) ? We1 : We2;
    int kdim = kk * 32 + (lane >> 4) * 8 + j;
    int ncol = t * 16 + (lane & 15);
    Bpack[idx] = f2bf(We[kdim * 128 + ncol]);
}

// ---------------- edge GEMM via MFMA: e_sorted = edge_attr[eid] @ We ----------------
// Output in dst-sorted order, bf16, [E][128].
__global__ __launch_bounds__(256) void e_gemm_mfma_kernel(
    const float* __restrict__ edge_attr, const int* __restrict__ eid, int E,
    const ushort_t* __restrict__ Bpack, ushort_t* __restrict__ e_out)
{
    __shared__ ushort_t ctile[4][16][136];   // +8 pad; row stride 272B (16B-mult)
    int wave = threadIdx.x >> 6;
    int lane = threadIdx.x & 63;
    int m0 = blockIdx.x * 64 + wave * 16;

    int mrow = m0 + (lane & 15);
    int row = eid[min(mrow, E - 1)];
    const float* arow = edge_attr + (size_t)row * 64;
    int koff = (lane >> 4) * 8;

    // A fragments: 8 contiguous f32 -> bf16x8, for k0=0 and k0=32
    float4 f0a = *(const float4*)(arow + koff);
    float4 f0b = *(const float4*)(arow + koff + 4);
    float4 f1a = *(const float4*)(arow + 32 + koff);
    float4 f1b = *(const float4*)(arow + 32 + koff + 4);
    short8 a0, a1;
    a0[0] = f2bf(f0a.x); a0[1] = f2bf(f0a.y); a0[2] = f2bf(f0a.z); a0[3] = f2bf(f0a.w);
    a0[4] = f2bf(f0b.x); a0[5] = f2bf(f0b.y); a0[6] = f2bf(f0b.z); a0[7] = f2bf(f0b.w);
    a1[0] = f2bf(f1a.x); a1[1] = f2bf(f1a.y); a1[2] = f2bf(f1a.z); a1[3] = f2bf(f1a.w);
    a1[4] = f2bf(f1b.x); a1[5] = f2bf(f1b.y); a1[6] = f2bf(f1b.z); a1[7] = f2bf(f1b.w);

    const short8* Bp = (const short8*)Bpack;
    f32x4 acc[8];
#pragma unroll
    for (int t = 0; t < 8; t++) acc[t] = (f32x4){0.f, 0.f, 0.f, 0.f};
#pragma unroll
    for (int t = 0; t < 8; t++) {
        short8 b0 = Bp[(t * 2 + 0) * 64 + lane];
        short8 b1 = Bp[(t * 2 + 1) * 64 + lane];
        acc[t] = __builtin_amdgcn_mfma_f32_16x16x32_bf16(a0, b0, acc[t], 0, 0, 0);
        acc[t] = __builtin_amdgcn_mfma_f32_16x16x32_bf16(a1, b1, acc[t], 0, 0, 0);
    }

    // epilogue: repack C through LDS for coalesced stores
    int crow = (lane >> 4) * 4;      // C/D: col=lane&15, row=(lane>>4)*4+reg
    int ccol = lane & 15;
#pragma unroll
    for (int t = 0; t < 8; t++) {
#pragma unroll
        for (int r = 0; r < 4; r++)
            ctile[wave][crow + r][t * 16 + ccol] = f2bf(acc[t][r]);
    }
    __syncthreads();
#pragma unroll
    for (int it = 0; it < 4; it++) {
        int rrow = it * 4 + (lane >> 4);
        int chunk = lane & 15;
        short8 vv = *(const short8*)&ctile[wave][rrow][chunk * 8];
        int gr = m0 + rrow;
        if (gr < E)
            *(short8*)(e_out + (size_t)gr * 128 + chunk * 8) = vv;
    }
}

// ---------------- aggregation: segment softmax + message sum + skip ----------------
__global__ __launch_bounds__(256) void agg_kernel(
    const int* __restrict__ row_ptr, const int* __restrict__ srcs,
    const float* __restrict__ q, const float* __restrict__ k,
    const float* __restrict__ v, const ushort_t* __restrict__ e,
    float* __restrict__ hout, int N)
{
    int wave = threadIdx.x >> 6;
    int lane = threadIdx.x & 63;
    int n = blockIdx.x * 4 + wave;
    if (n >= N) return;

    const float2* q2 = (const float2*)q;
    const float2* k2 = (const float2*)k;
    const float2* v2 = (const float2*)v;
    const unsigned int* e32 = (const unsigned int*)e;
    float2* h2 = (float2*)hout;

    float2 qq = q2[(size_t)n * 64 + lane];
    float2 sk = h2[(size_t)n * 64 + lane];
    float acc0 = 0.f, acc1 = 0.f, sw = 0.f;
    int jb = row_ptr[n], je = row_ptr[n + 1];
    for (int j = jb; j < je; ++j) {
        int s = srcs[j];
        unsigned int ee = e32[(size_t)j * 64 + lane];
        float e0 = __uint_as_float(ee << 16);
        float e1 = __uint_as_float(ee & 0xffff0000u);
        float2 kk = k2[(size_t)s * 64 + lane];
        float2 vv = v2[(size_t)s * 64 + lane];
        float part = qq.x * (kk.x + e0) + qq.y * (kk.y + e1);
        part += __shfl_xor(part, 1);
        part += __shfl_xor(part, 2);
        part += __shfl_xor(part, 4);
        float w = __expf(part * 0.25f);   // 1/sqrt(16)
        acc0 += w * (vv.x + e0);
        acc1 += w * (vv.y + e1);
        sw += w;
    }
    float inv = 1.0f / (sw + 1e-16f);
    float2 o;
    o.x = acc0 * inv + sk.x;
    o.y = acc1 * inv + sk.y;
    h2[(size_t)n * 64 + lane] = o;
}

// ---------------- BatchNorm + ReLU ----------------
__global__ __launch_bounds__(128) void bn_stats_kernel(const float* __restrict__ h, int N,
                                                       float* __restrict__ sums) {
    int f = threadIdx.x;  // 128
    float s = 0.f, s2 = 0.f;
    for (int n = blockIdx.x; n < N; n += gridDim.x) {
        float x = h[(size_t)n * 128 + f];
        s += x;
        s2 += x * x;
    }
    atomicAdd(&sums[f], s);
    atomicAdd(&sums[128 + f], s2);
}

__global__ __launch_bounds__(256) void bn_apply_kernel(
    const float* __restrict__ h, const float* __restrict__ sums,
    const float* __restrict__ g, const float* __restrict__ be,
    float* __restrict__ out, int N)
{
    int idx = blockIdx.x * blockDim.x + threadIdx.x;
    if (idx >= N * 128) return;
    int f = idx & 127;
    float invN = 1.0f / (float)N;
    float mu = sums[f] * invN;
    float var = sums[128 + f] * invN - mu * mu;
    float x = (h[idx] - mu) * rsqrtf(var + 1e-5f) * g[f] + be[f];
    out[idx] = fmaxf(x, 0.f);
}

// ---------------------------------------------------------------------------
extern "C" void kernel_launch(void* const* d_in, const int* in_sizes, int n_in,
                              void* d_out, int out_size, void* d_ws, size_t ws_size,
                              hipStream_t stream)
{
    const float* x = (const float*)d_in[0];
    const int* edge_index = (const int*)d_in[1];
    const float* edge_attr = (const float*)d_in[2];
    int N = in_sizes[0] / 64;
    int E = in_sizes[1] / 2;
    const int* src = edge_index;
    const int* dst = edge_index + E;

    const float* W[3][9];
    for (int l = 0; l < 3; l++)
        for (int i = 0; i < 9; i++) W[l][i] = (const float*)d_in[3 + l * 9 + i];
    // W indices: 0:Wq 1:bq 2:Wk 3:bk 4:Wv 5:bv 6:We 7:Ws 8:bs
    const float* g0 = (const float*)d_in[30];
    const float* be0 = (const float*)d_in[31];
    const float* g1 = (const float*)d_in[32];
    const float* be1 = (const float*)d_in[33];

    char* p = (char*)d_ws;
    auto alloc = [&](size_t bytes) -> char* {
        char* r = p;
        p += (bytes + 255) & ~(size_t)255;
        return r;
    };
    float* q = (float*)alloc((size_t)N * 128 * 4);
    float* k = (float*)alloc((size_t)N * 128 * 4);
    float* v = (float*)alloc((size_t)N * 128 * 4);
    float* A = (float*)alloc((size_t)N * 128 * 4);
    float* B = (float*)alloc((size_t)N * 128 * 4);
    ushort_t* e = (ushort_t*)alloc((size_t)E * 128 * 2);
    int* row_ptr = (int*)alloc((size_t)(N + 1) * 4);
    int* cursor = (int*)alloc((size_t)N * 4);
    int* histb = (int*)alloc((size_t)N * 4);
    int* eid = (int*)alloc((size_t)E * 4);
    int* srcs = (int*)alloc((size_t)E * 4);
    float* sums = (float*)alloc(256 * 4);
    ushort_t* Bpack = (ushort_t*)alloc((size_t)3 * 8192 * 2);

    // ---- CSR build (per call; graph is fixed input) ----
    hipMemsetAsync(histb, 0, (size_t)N * 4, stream);
    hist_kernel<<<(E + 255) / 256, 256, 0, stream>>>(dst, E, histb);
    scan_kernel<<<1, 1024, 0, stream>>>(histb, N, E, row_ptr, cursor);
    scatter_kernel<<<(E + 255) / 256, 256, 0, stream>>>(src, dst, E, cursor, eid, srcs);
    pack_We_kernel<<<(3 * 8192 + 255) / 256, 256, 0, stream>>>(W[0][6], W[1][6], W[2][6], Bpack);

    for (int l = 0; l < 3; l++) {
        const float* hin = (l == 0) ? x : A;
        float* skipbuf = (l == 2) ? (float*)d_out : B;
        if (l == 0)
            node_gemm_kernel<64><<<(N + 15) / 16, 128, 0, stream>>>(
                hin, N, W[l][0], W[l][1], W[l][2], W[l][3], W[l][4], W[l][5], W[l][7], W[l][8],
                q, k, v, skipbuf);
        else
            node_gemm_kernel<128><<<(N + 15) / 16, 128, 0, stream>>>(
                hin, N, W[l][0], W[l][1], W[l][2], W[l][3], W[l][4], W[l][5], W[l][7], W[l][8],
                q, k, v, skipbuf);
        e_gemm_mfma_kernel<<<(E + 63) / 64, 256, 0, stream>>>(
            edge_attr, eid, E, Bpack + (size_t)l * 8192, e);
        agg_kernel<<<(N + 3) / 4, 256, 0, stream>>>(row_ptr, srcs, q, k, v, e, skipbuf, N);
        if (l < 2) {
            hipMemsetAsync(sums, 0, 256 * 4, stream);
            bn_stats_kernel<<<256, 128, 0, stream>>>(skipbuf, N, sums);
            const float* gg = (l == 0) ? g0 : g1;
            const float* bb = (l == 0) ? be0 : be1;
            bn_apply_kernel<<<((size_t)N * 128 + 255) / 256, 256, 0, stream>>>(skipbuf, sums, gg, bb, A, N);
        }
    }

    // ---- second output: edge_attr passthrough ----
    hipMemcpyAsync((float*)d_out + (size_t)N * 128, edge_attr, (size_t)E * 64 * 4,
                   hipMemcpyDeviceToDevice, stream);
}

// Round 3
// 1402.332 us; speedup vs baseline: 2.4935x; 1.2225x over previous
//
#include <hip/hip_runtime.h>
#include <hip/hip_bf16.h>

typedef __attribute__((ext_vector_type(8))) short short8;
typedef __attribute__((ext_vector_type(4))) float f32x4;
typedef unsigned short ushort_t;

static __device__ __forceinline__ ushort_t f2bf(float x) {
    __hip_bfloat16 h = __float2bfloat16(x);
    return *(ushort_t*)&h;
}
static __device__ __forceinline__ float bflo(unsigned int u) { return __uint_as_float(u << 16); }
static __device__ __forceinline__ float bfhi(unsigned int u) { return __uint_as_float(u & 0xffff0000u); }

// ---------------------------------------------------------------------------
// GraphTransformer: 3x TransformerConv(H=8,c=16) + BN/ReLU, fixed graph.
// CSR build once; per layer: fused node GEMM (MFMA, q|k|v|skip), edge GEMM
// (MFMA), wave-per-node segment-softmax aggregation (bf16 k/v/e gathers),
// BN+ReLU.
// ---------------------------------------------------------------------------

// ---------------- CSR build ----------------
__global__ void hist_kernel(const int* __restrict__ dst, int E, int* __restrict__ hist) {
    int i = blockIdx.x * blockDim.x + threadIdx.x;
    if (i < E) atomicAdd(&hist[dst[i]], 1);
}

__global__ __launch_bounds__(1024) void scan_kernel(const int* __restrict__ hist, int n, int total,
                                                    int* __restrict__ row_ptr, int* __restrict__ cursor) {
    __shared__ int lds[1024];
    __shared__ int s_running;
    int tid = threadIdx.x;
    if (tid == 0) s_running = 0;
    __syncthreads();
    for (int base = 0; base < n; base += 1024) {
        int i = base + tid;
        int vv = (i < n) ? hist[i] : 0;
        lds[tid] = vv;
        __syncthreads();
        for (int off = 1; off < 1024; off <<= 1) {
            int t = (tid >= off) ? lds[tid - off] : 0;
            __syncthreads();
            lds[tid] += t;
            __syncthreads();
        }
        int excl = lds[tid] - vv;
        int run = s_running;
        if (i < n) { row_ptr[i] = run + excl; cursor[i] = run + excl; }
        __syncthreads();
        if (tid == 0) s_running = run + lds[1023];
        __syncthreads();
    }
    if (tid == 0) row_ptr[n] = total;
}

__global__ void scatter_kernel(const int* __restrict__ src, const int* __restrict__ dst, int E,
                               int* __restrict__ cursor, int* __restrict__ eid, int* __restrict__ srcs) {
    int i = blockIdx.x * blockDim.x + threadIdx.x;
    if (i < E) {
        int d = dst[i];
        int pos = atomicAdd(&cursor[d], 1);
        eid[pos] = i;
        srcs[pos] = src[i];
    }
}

// ---------------- weight packing ----------------
// Node weights: concat [DI,512] = Wq|Wk|Wv|Ws -> B fragments for 16x16x32.
// dst[(t*NKF+kf)*512 + lane*8 + j] = bf16(W[kf*32 + (lane>>4)*8 + j][t*16 + (lane&15)])
__global__ __launch_bounds__(256) void pack_Wnode_kernel(
    const float* __restrict__ Wq, const float* __restrict__ Wk,
    const float* __restrict__ Wv, const float* __restrict__ Ws,
    int DI, ushort_t* __restrict__ dst)
{
    int NKF = DI >> 5;
    int total = DI * 512;
    int idx = blockIdx.x * blockDim.x + threadIdx.x;
    if (idx >= total) return;
    int j = idx & 7;
    int lane = (idx >> 3) & 63;
    int rest = idx >> 9;
    int kf = rest % NKF;
    int t = rest / NKF;
    int kdim = kf * 32 + (lane >> 4) * 8 + j;
    int ncol = t * 16 + (lane & 15);
    const float* W = (ncol < 128) ? Wq : (ncol < 256) ? Wk : (ncol < 384) ? Wv : Ws;
    dst[idx] = f2bf(W[kdim * 128 + (ncol & 127)]);
}

__global__ __launch_bounds__(256) void pack_bias_kernel(
    const float* __restrict__ bq, const float* __restrict__ bk,
    const float* __restrict__ bv, const float* __restrict__ bs,
    float* __restrict__ dst)
{
    int i = threadIdx.x + blockIdx.x * blockDim.x;
    if (i >= 512) return;
    const float* b = (i < 128) ? bq : (i < 256) ? bk : (i < 384) ? bv : bs;
    dst[i] = b[i & 127];
}

// Edge weights: [64,128] -> B fragments.
__global__ __launch_bounds__(256) void pack_We_kernel(
    const float* __restrict__ We0, const float* __restrict__ We1,
    const float* __restrict__ We2, ushort_t* __restrict__ Bpack)
{
    int idx = blockIdx.x * blockDim.x + threadIdx.x;
    if (idx >= 3 * 8192) return;
    int j = idx & 7;
    int lane = (idx >> 3) & 63;
    int kk = (idx >> 9) & 1;
    int t = (idx >> 10) & 7;
    int layer = idx >> 13;
    const float* We = (layer == 0) ? We0 : (layer == 1) ? We1 : We2;
    int kdim = kk * 32 + (lane >> 4) * 8 + j;
    int ncol = t * 16 + (lane & 15);
    Bpack[idx] = f2bf(We[kdim * 128 + ncol]);
}

// ---------------- fused node GEMM via MFMA ----------------
// [N,DI] @ [DI,512] + bias -> q (f32), k (bf16), v (bf16), skip (f32)
template <int DI>
__global__ __launch_bounds__(256) void node_gemm_mfma_kernel(
    const float* __restrict__ hin, int N,
    const ushort_t* __restrict__ Bpack, const float* __restrict__ biasc,
    float* __restrict__ qout, ushort_t* __restrict__ kout,
    ushort_t* __restrict__ vout, float* __restrict__ skipout)
{
    constexpr int NKF = DI / 32;
    __shared__ float ctile[64][132];
    int wave = threadIdx.x >> 6;
    int lane = threadIdx.x & 63;
    int tid = threadIdx.x;
    int base = blockIdx.x * 64;
    int m0 = base + wave * 16;

    int mrow = min(m0 + (lane & 15), N - 1);
    const float* arow = hin + (size_t)mrow * DI;
    int koff = (lane >> 4) * 8;

    short8 a[NKF];
#pragma unroll
    for (int kf = 0; kf < NKF; kf++) {
        float4 fa = *(const float4*)(arow + kf * 32 + koff);
        float4 fb = *(const float4*)(arow + kf * 32 + koff + 4);
        short8 t;
        t[0] = f2bf(fa.x); t[1] = f2bf(fa.y); t[2] = f2bf(fa.z); t[3] = f2bf(fa.w);
        t[4] = f2bf(fb.x); t[5] = f2bf(fb.y); t[6] = f2bf(fb.z); t[7] = f2bf(fb.w);
        a[kf] = t;
    }

    const short8* Bp = (const short8*)Bpack;
    f32x4 acc[32];
#pragma unroll
    for (int t = 0; t < 32; t++) acc[t] = (f32x4){0.f, 0.f, 0.f, 0.f};
#pragma unroll
    for (int t = 0; t < 32; t++) {
#pragma unroll
        for (int kf = 0; kf < NKF; kf++)
            acc[t] = __builtin_amdgcn_mfma_f32_16x16x32_bf16(a[kf], Bp[(t * NKF + kf) * 64 + lane], acc[t], 0, 0, 0);
    }

    int crow = (lane >> 4) * 4;   // C/D: col=lane&15, row=(lane>>4)*4+reg
    int ccol = lane & 15;
#pragma unroll
    for (int osel = 0; osel < 4; osel++) {
        // write this output's 8 tiles (+bias) to LDS
#pragma unroll
        for (int t8 = 0; t8 < 8; t8++) {
            float bb = biasc[osel * 128 + t8 * 16 + ccol];
#pragma unroll
            for (int r = 0; r < 4; r++)
                ctile[wave * 16 + crow + r][t8 * 16 + ccol] = acc[osel * 8 + t8][r] + bb;
        }
        __syncthreads();
        if (osel == 0 || osel == 3) {
            float* out = (osel == 0) ? qout : skipout;
#pragma unroll
            for (int it = 0; it < 8; it++) {
                int idx4 = it * 256 + tid;
                int row = idx4 >> 5;
                int c4 = idx4 & 31;
                int gr = base + row;
                if (gr < N) {
                    float4 vv = *(const float4*)&ctile[row][c4 * 4];
                    *(float4*)(out + (size_t)gr * 128 + c4 * 4) = vv;
                }
            }
        } else {
            ushort_t* out = (osel == 1) ? kout : vout;
#pragma unroll
            for (int it = 0; it < 4; it++) {
                int idx8 = it * 256 + tid;
                int row = idx8 >> 4;
                int c8 = idx8 & 15;
                int gr = base + row;
                if (gr < N) {
                    const float* s = &ctile[row][c8 * 8];
                    short8 vv;
#pragma unroll
                    for (int jj = 0; jj < 8; jj++) vv[jj] = f2bf(s[jj]);
                    *(short8*)(out + (size_t)gr * 128 + c8 * 8) = vv;
                }
            }
        }
        __syncthreads();
    }
}

// ---------------- edge GEMM via MFMA: e_sorted = edge_attr[eid] @ We ----------------
__global__ __launch_bounds__(256) void e_gemm_mfma_kernel(
    const float* __restrict__ edge_attr, const int* __restrict__ eid, int E,
    const ushort_t* __restrict__ Bpack, ushort_t* __restrict__ e_out)
{
    __shared__ ushort_t ctile[4][16][136];
    int wave = threadIdx.x >> 6;
    int lane = threadIdx.x & 63;
    int m0 = blockIdx.x * 64 + wave * 16;

    int mrow = m0 + (lane & 15);
    int row = eid[min(mrow, E - 1)];
    const float* arow = edge_attr + (size_t)row * 64;
    int koff = (lane >> 4) * 8;

    float4 f0a = *(const float4*)(arow + koff);
    float4 f0b = *(const float4*)(arow + koff + 4);
    float4 f1a = *(const float4*)(arow + 32 + koff);
    float4 f1b = *(const float4*)(arow + 32 + koff + 4);
    short8 a0, a1;
    a0[0] = f2bf(f0a.x); a0[1] = f2bf(f0a.y); a0[2] = f2bf(f0a.z); a0[3] = f2bf(f0a.w);
    a0[4] = f2bf(f0b.x); a0[5] = f2bf(f0b.y); a0[6] = f2bf(f0b.z); a0[7] = f2bf(f0b.w);
    a1[0] = f2bf(f1a.x); a1[1] = f2bf(f1a.y); a1[2] = f2bf(f1a.z); a1[3] = f2bf(f1a.w);
    a1[4] = f2bf(f1b.x); a1[5] = f2bf(f1b.y); a1[6] = f2bf(f1b.z); a1[7] = f2bf(f1b.w);

    const short8* Bp = (const short8*)Bpack;
    f32x4 acc[8];
#pragma unroll
    for (int t = 0; t < 8; t++) acc[t] = (f32x4){0.f, 0.f, 0.f, 0.f};
#pragma unroll
    for (int t = 0; t < 8; t++) {
        short8 b0 = Bp[(t * 2 + 0) * 64 + lane];
        short8 b1 = Bp[(t * 2 + 1) * 64 + lane];
        acc[t] = __builtin_amdgcn_mfma_f32_16x16x32_bf16(a0, b0, acc[t], 0, 0, 0);
        acc[t] = __builtin_amdgcn_mfma_f32_16x16x32_bf16(a1, b1, acc[t], 0, 0, 0);
    }

    int crow = (lane >> 4) * 4;
    int ccol = lane & 15;
#pragma unroll
    for (int t = 0; t < 8; t++) {
#pragma unroll
        for (int r = 0; r < 4; r++)
            ctile[wave][crow + r][t * 16 + ccol] = f2bf(acc[t][r]);
    }
    __syncthreads();
#pragma unroll
    for (int it = 0; it < 4; it++) {
        int rrow = it * 4 + (lane >> 4);
        int chunk = lane & 15;
        short8 vv = *(const short8*)&ctile[wave][rrow][chunk * 8];
        int gr = m0 + rrow;
        if (gr < E)
            *(short8*)(e_out + (size_t)gr * 128 + chunk * 8) = vv;
    }
}

// ---------------- aggregation: segment softmax + message sum + skip ----------------
__global__ __launch_bounds__(256) void agg_kernel(
    const int* __restrict__ row_ptr, const int* __restrict__ srcs,
    const float* __restrict__ q, const ushort_t* __restrict__ k,
    const ushort_t* __restrict__ v, const ushort_t* __restrict__ e,
    float* __restrict__ hout, int N)
{
    int wave = threadIdx.x >> 6;
    int lane = threadIdx.x & 63;
    int n = blockIdx.x * 4 + wave;
    if (n >= N) return;

    const float2* q2 = (const float2*)q;
    const unsigned int* k32 = (const unsigned int*)k;
    const unsigned int* v32 = (const unsigned int*)v;
    const unsigned int* e32 = (const unsigned int*)e;
    float2* h2 = (float2*)hout;

    float2 qq = q2[(size_t)n * 64 + lane];
    float2 sk = h2[(size_t)n * 64 + lane];
    float acc0 = 0.f, acc1 = 0.f, sw = 0.f;
    int jb = row_ptr[n], je = row_ptr[n + 1];
    for (int j = jb; j < je; ++j) {
        int s = srcs[j];
        unsigned int ee = e32[(size_t)j * 64 + lane];
        unsigned int ku = k32[(size_t)s * 64 + lane];
        unsigned int vu = v32[(size_t)s * 64 + lane];
        float e0 = bflo(ee), e1 = bfhi(ee);
        float part = qq.x * (bflo(ku) + e0) + qq.y * (bfhi(ku) + e1);
        part += __shfl_xor(part, 1);
        part += __shfl_xor(part, 2);
        part += __shfl_xor(part, 4);
        float w = __expf(part * 0.25f);   // 1/sqrt(16)
        acc0 += w * (bflo(vu) + e0);
        acc1 += w * (bfhi(vu) + e1);
        sw += w;
    }
    float inv = 1.0f / (sw + 1e-16f);
    float2 o;
    o.x = acc0 * inv + sk.x;
    o.y = acc1 * inv + sk.y;
    h2[(size_t)n * 64 + lane] = o;
}

// ---------------- BatchNorm + ReLU ----------------
__global__ __launch_bounds__(128) void bn_stats_kernel(const float* __restrict__ h, int N,
                                                       float* __restrict__ sums) {
    int f = threadIdx.x;
    float s = 0.f, s2 = 0.f;
    for (int n = blockIdx.x; n < N; n += gridDim.x) {
        float x = h[(size_t)n * 128 + f];
        s += x;
        s2 += x * x;
    }
    atomicAdd(&sums[f], s);
    atomicAdd(&sums[128 + f], s2);
}

__global__ __launch_bounds__(256) void bn_apply_kernel(
    const float* __restrict__ h, const float* __restrict__ sums,
    const float* __restrict__ g, const float* __restrict__ be,
    float* __restrict__ out, int N)
{
    int idx = blockIdx.x * blockDim.x + threadIdx.x;
    if (idx >= N * 128) return;
    int f = idx & 127;
    float invN = 1.0f / (float)N;
    float mu = sums[f] * invN;
    float var = sums[128 + f] * invN - mu * mu;
    float x = (h[idx] - mu) * rsqrtf(var + 1e-5f) * g[f] + be[f];
    out[idx] = fmaxf(x, 0.f);
}

// ---------------------------------------------------------------------------
extern "C" void kernel_launch(void* const* d_in, const int* in_sizes, int n_in,
                              void* d_out, int out_size, void* d_ws, size_t ws_size,
                              hipStream_t stream)
{
    const float* x = (const float*)d_in[0];
    const int* edge_index = (const int*)d_in[1];
    const float* edge_attr = (const float*)d_in[2];
    int N = in_sizes[0] / 64;
    int E = in_sizes[1] / 2;
    const int* src = edge_index;
    const int* dst = edge_index + E;

    const float* W[3][9];
    for (int l = 0; l < 3; l++)
        for (int i = 0; i < 9; i++) W[l][i] = (const float*)d_in[3 + l * 9 + i];
    // 0:Wq 1:bq 2:Wk 3:bk 4:Wv 5:bv 6:We 7:Ws 8:bs
    const float* g0 = (const float*)d_in[30];
    const float* be0 = (const float*)d_in[31];
    const float* g1 = (const float*)d_in[32];
    const float* be1 = (const float*)d_in[33];

    char* p = (char*)d_ws;
    auto alloc = [&](size_t bytes) -> char* {
        char* r = p;
        p += (bytes + 255) & ~(size_t)255;
        return r;
    };
    float* q = (float*)alloc((size_t)N * 128 * 4);
    ushort_t* k = (ushort_t*)alloc((size_t)N * 128 * 2);
    ushort_t* v = (ushort_t*)alloc((size_t)N * 128 * 2);
    float* A = (float*)alloc((size_t)N * 128 * 4);
    float* B = (float*)alloc((size_t)N * 128 * 4);
    ushort_t* e = (ushort_t*)alloc((size_t)E * 128 * 2);
    int* row_ptr = (int*)alloc((size_t)(N + 1) * 4);
    int* cursor = (int*)alloc((size_t)N * 4);
    int* histb = (int*)alloc((size_t)N * 4);
    int* eid = (int*)alloc((size_t)E * 4);
    int* srcs = (int*)alloc((size_t)E * 4);
    float* sums = (float*)alloc(256 * 4);
    ushort_t* BpackE = (ushort_t*)alloc((size_t)3 * 8192 * 2);
    ushort_t* BpackN = (ushort_t*)alloc((size_t)3 * 65536 * 2);
    float* biasc = (float*)alloc((size_t)3 * 512 * 4);

    // ---- CSR build ----
    hipMemsetAsync(histb, 0, (size_t)N * 4, stream);
    hist_kernel<<<(E + 255) / 256, 256, 0, stream>>>(dst, E, histb);
    scan_kernel<<<1, 1024, 0, stream>>>(histb, N, E, row_ptr, cursor);
    scatter_kernel<<<(E + 255) / 256, 256, 0, stream>>>(src, dst, E, cursor, eid, srcs);

    // ---- weight packing ----
    pack_We_kernel<<<(3 * 8192 + 255) / 256, 256, 0, stream>>>(W[0][6], W[1][6], W[2][6], BpackE);
    for (int l = 0; l < 3; l++) {
        int DI = (l == 0) ? 64 : 128;
        pack_Wnode_kernel<<<(DI * 512 + 255) / 256, 256, 0, stream>>>(
            W[l][0], W[l][2], W[l][4], W[l][7], DI, BpackN + (size_t)l * 65536);
        pack_bias_kernel<<<2, 256, 0, stream>>>(W[l][1], W[l][3], W[l][5], W[l][8],
                                                biasc + (size_t)l * 512);
    }

    for (int l = 0; l < 3; l++) {
        const float* hin = (l == 0) ? x : A;
        float* skipbuf = (l == 2) ? (float*)d_out : B;
        if (l == 0)
            node_gemm_mfma_kernel<64><<<(N + 63) / 64, 256, 0, stream>>>(
                hin, N, BpackN, biasc, q, k, v, skipbuf);
        else
            node_gemm_mfma_kernel<128><<<(N + 63) / 64, 256, 0, stream>>>(
                hin, N, BpackN + (size_t)l * 65536, biasc + (size_t)l * 512, q, k, v, skipbuf);
        e_gemm_mfma_kernel<<<(E + 63) / 64, 256, 0, stream>>>(
            edge_attr, eid, E, BpackE + (size_t)l * 8192, e);
        agg_kernel<<<(N + 3) / 4, 256, 0, stream>>>(row_ptr, srcs, q, k, v, e, skipbuf, N);
        if (l < 2) {
            hipMemsetAsync(sums, 0, 256 * 4, stream);
            bn_stats_kernel<<<256, 128, 0, stream>>>(skipbuf, N, sums);
            const float* gg = (l == 0) ? g0 : g1;
            const float* bb = (l == 0) ? be0 : be1;
            bn_apply_kernel<<<((size_t)N * 128 + 255) / 256, 256, 0, stream>>>(skipbuf, sums, gg, bb, A, N);
        }
    }

    // ---- second output: edge_attr passthrough ----
    hipMemcpyAsync((float*)d_out + (size_t)N * 128, edge_attr, (size_t)E * 64 * 4,
                   hipMemcpyDeviceToDevice, stream);
}

// Round 4
// 1238.115 us; speedup vs baseline: 2.8243x; 1.1326x over previous
//
#include <hip/hip_runtime.h>
#include <hip/hip_bf16.h>

typedef __attribute__((ext_vector_type(8))) short short8;
typedef __attribute__((ext_vector_type(4))) float f32x4;
typedef unsigned short ushort_t;

static __device__ __forceinline__ ushort_t f2bf(float x) {
    __hip_bfloat16 h = __float2bfloat16(x);
    return *(ushort_t*)&h;
}
static __device__ __forceinline__ float bflo(unsigned int u) { return __uint_as_float(u << 16); }
static __device__ __forceinline__ float bfhi(unsigned int u) { return __uint_as_float(u & 0xffff0000u); }

// ---------------------------------------------------------------------------
// GraphTransformer: 3x TransformerConv(H=8,c=16) + BN/ReLU, fixed graph.
// ---------------------------------------------------------------------------

// ---------------- CSR build ----------------
__global__ void hist_kernel(const int* __restrict__ dst, int E, int* __restrict__ hist) {
    int i = blockIdx.x * blockDim.x + threadIdx.x;
    if (i < E) atomicAdd(&hist[dst[i]], 1);
}

__global__ __launch_bounds__(1024) void scan_kernel(const int* __restrict__ hist, int n, int total,
                                                    int* __restrict__ row_ptr, int* __restrict__ cursor) {
    __shared__ int lds[1024];
    __shared__ int s_running;
    int tid = threadIdx.x;
    if (tid == 0) s_running = 0;
    __syncthreads();
    for (int base = 0; base < n; base += 1024) {
        int i = base + tid;
        int vv = (i < n) ? hist[i] : 0;
        lds[tid] = vv;
        __syncthreads();
        for (int off = 1; off < 1024; off <<= 1) {
            int t = (tid >= off) ? lds[tid - off] : 0;
            __syncthreads();
            lds[tid] += t;
            __syncthreads();
        }
        int excl = lds[tid] - vv;
        int run = s_running;
        if (i < n) { row_ptr[i] = run + excl; cursor[i] = run + excl; }
        __syncthreads();
        if (tid == 0) s_running = run + lds[1023];
        __syncthreads();
    }
    if (tid == 0) row_ptr[n] = total;
}

__global__ void scatter_kernel(const int* __restrict__ src, const int* __restrict__ dst, int E,
                               int* __restrict__ cursor, int* __restrict__ eid, int* __restrict__ srcs) {
    int i = blockIdx.x * blockDim.x + threadIdx.x;
    if (i < E) {
        int d = dst[i];
        int pos = atomicAdd(&cursor[d], 1);
        eid[pos] = i;
        srcs[pos] = src[i];
    }
}

// ---------------- weight packing ----------------
__global__ __launch_bounds__(256) void pack_Wnode_kernel(
    const float* __restrict__ Wq, const float* __restrict__ Wk,
    const float* __restrict__ Wv, const float* __restrict__ Ws,
    int DI, ushort_t* __restrict__ dst)
{
    int NKF = DI >> 5;
    int total = DI * 512;
    int idx = blockIdx.x * blockDim.x + threadIdx.x;
    if (idx >= total) return;
    int j = idx & 7;
    int lane = (idx >> 3) & 63;
    int rest = idx >> 9;
    int kf = rest % NKF;
    int t = rest / NKF;
    int kdim = kf * 32 + (lane >> 4) * 8 + j;
    int ncol = t * 16 + (lane & 15);
    const float* W = (ncol < 128) ? Wq : (ncol < 256) ? Wk : (ncol < 384) ? Wv : Ws;
    dst[idx] = f2bf(W[kdim * 128 + (ncol & 127)]);
}

__global__ __launch_bounds__(256) void pack_bias_kernel(
    const float* __restrict__ bq, const float* __restrict__ bk,
    const float* __restrict__ bv, const float* __restrict__ bs,
    float* __restrict__ dst)
{
    int i = threadIdx.x + blockIdx.x * blockDim.x;
    if (i >= 512) return;
    const float* b = (i < 128) ? bq : (i < 256) ? bk : (i < 384) ? bv : bs;
    dst[i] = b[i & 127];
}

__global__ __launch_bounds__(256) void pack_We_kernel(
    const float* __restrict__ We0, const float* __restrict__ We1,
    const float* __restrict__ We2, ushort_t* __restrict__ Bpack)
{
    int idx = blockIdx.x * blockDim.x + threadIdx.x;
    if (idx >= 3 * 8192) return;
    int j = idx & 7;
    int lane = (idx >> 3) & 63;
    int kk = (idx >> 9) & 1;
    int t = (idx >> 10) & 7;
    int layer = idx >> 13;
    const float* We = (layer == 0) ? We0 : (layer == 1) ? We1 : We2;
    int kdim = kk * 32 + (lane >> 4) * 8 + j;
    int ncol = t * 16 + (lane & 15);
    Bpack[idx] = f2bf(We[kdim * 128 + ncol]);
}

// ---------------- fused node GEMM via MFMA ----------------
template <int DI>
__global__ __launch_bounds__(256) void node_gemm_mfma_kernel(
    const float* __restrict__ hin, int N,
    const ushort_t* __restrict__ Bpack, const float* __restrict__ biasc,
    float* __restrict__ qout, ushort_t* __restrict__ kout,
    ushort_t* __restrict__ vout, float* __restrict__ skipout)
{
    constexpr int NKF = DI / 32;
    __shared__ float ctile[64][132];
    int wave = threadIdx.x >> 6;
    int lane = threadIdx.x & 63;
    int tid = threadIdx.x;
    int base = blockIdx.x * 64;
    int m0 = base + wave * 16;

    int mrow = min(m0 + (lane & 15), N - 1);
    const float* arow = hin + (size_t)mrow * DI;
    int koff = (lane >> 4) * 8;

    short8 a[NKF];
#pragma unroll
    for (int kf = 0; kf < NKF; kf++) {
        float4 fa = *(const float4*)(arow + kf * 32 + koff);
        float4 fb = *(const float4*)(arow + kf * 32 + koff + 4);
        short8 t;
        t[0] = f2bf(fa.x); t[1] = f2bf(fa.y); t[2] = f2bf(fa.z); t[3] = f2bf(fa.w);
        t[4] = f2bf(fb.x); t[5] = f2bf(fb.y); t[6] = f2bf(fb.z); t[7] = f2bf(fb.w);
        a[kf] = t;
    }

    const short8* Bp = (const short8*)Bpack;
    f32x4 acc[32];
#pragma unroll
    for (int t = 0; t < 32; t++) acc[t] = (f32x4){0.f, 0.f, 0.f, 0.f};
#pragma unroll
    for (int t = 0; t < 32; t++) {
#pragma unroll
        for (int kf = 0; kf < NKF; kf++)
            acc[t] = __builtin_amdgcn_mfma_f32_16x16x32_bf16(a[kf], Bp[(t * NKF + kf) * 64 + lane], acc[t], 0, 0, 0);
    }

    int crow = (lane >> 4) * 4;
    int ccol = lane & 15;
#pragma unroll
    for (int osel = 0; osel < 4; osel++) {
#pragma unroll
        for (int t8 = 0; t8 < 8; t8++) {
            float bb = biasc[osel * 128 + t8 * 16 + ccol];
#pragma unroll
            for (int r = 0; r < 4; r++)
                ctile[wave * 16 + crow + r][t8 * 16 + ccol] = acc[osel * 8 + t8][r] + bb;
        }
        __syncthreads();
        if (osel == 0 || osel == 3) {
            float* out = (osel == 0) ? qout : skipout;
#pragma unroll
            for (int it = 0; it < 8; it++) {
                int idx4 = it * 256 + tid;
                int row = idx4 >> 5;
                int c4 = idx4 & 31;
                int gr = base + row;
                if (gr < N) {
                    float4 vv = *(const float4*)&ctile[row][c4 * 4];
                    *(float4*)(out + (size_t)gr * 128 + c4 * 4) = vv;
                }
            }
        } else {
            ushort_t* out = (osel == 1) ? kout : vout;
#pragma unroll
            for (int it = 0; it < 4; it++) {
                int idx8 = it * 256 + tid;
                int row = idx8 >> 4;
                int c8 = idx8 & 15;
                int gr = base + row;
                if (gr < N) {
                    const float* s = &ctile[row][c8 * 8];
                    short8 vv;
#pragma unroll
                    for (int jj = 0; jj < 8; jj++) vv[jj] = f2bf(s[jj]);
                    *(short8*)(out + (size_t)gr * 128 + c8 * 8) = vv;
                }
            }
        }
        __syncthreads();
    }
}

// ---------------- edge GEMM via MFMA ----------------
__global__ __launch_bounds__(256) void e_gemm_mfma_kernel(
    const float* __restrict__ edge_attr, const int* __restrict__ eid, int E,
    const ushort_t* __restrict__ Bpack, ushort_t* __restrict__ e_out)
{
    __shared__ ushort_t ctile[4][16][136];
    int wave = threadIdx.x >> 6;
    int lane = threadIdx.x & 63;
    int m0 = blockIdx.x * 64 + wave * 16;

    int mrow = m0 + (lane & 15);
    int row = eid[min(mrow, E - 1)];
    const float* arow = edge_attr + (size_t)row * 64;
    int koff = (lane >> 4) * 8;

    float4 f0a = *(const float4*)(arow + koff);
    float4 f0b = *(const float4*)(arow + koff + 4);
    float4 f1a = *(const float4*)(arow + 32 + koff);
    float4 f1b = *(const float4*)(arow + 32 + koff + 4);
    short8 a0, a1;
    a0[0] = f2bf(f0a.x); a0[1] = f2bf(f0a.y); a0[2] = f2bf(f0a.z); a0[3] = f2bf(f0a.w);
    a0[4] = f2bf(f0b.x); a0[5] = f2bf(f0b.y); a0[6] = f2bf(f0b.z); a0[7] = f2bf(f0b.w);
    a1[0] = f2bf(f1a.x); a1[1] = f2bf(f1a.y); a1[2] = f2bf(f1a.z); a1[3] = f2bf(f1a.w);
    a1[4] = f2bf(f1b.x); a1[5] = f2bf(f1b.y); a1[6] = f2bf(f1b.z); a1[7] = f2bf(f1b.w);

    const short8* Bp = (const short8*)Bpack;
    f32x4 acc[8];
#pragma unroll
    for (int t = 0; t < 8; t++) acc[t] = (f32x4){0.f, 0.f, 0.f, 0.f};
#pragma unroll
    for (int t = 0; t < 8; t++) {
        short8 b0 = Bp[(t * 2 + 0) * 64 + lane];
        short8 b1 = Bp[(t * 2 + 1) * 64 + lane];
        acc[t] = __builtin_amdgcn_mfma_f32_16x16x32_bf16(a0, b0, acc[t], 0, 0, 0);
        acc[t] = __builtin_amdgcn_mfma_f32_16x16x32_bf16(a1, b1, acc[t], 0, 0, 0);
    }

    int crow = (lane >> 4) * 4;
    int ccol = lane & 15;
#pragma unroll
    for (int t = 0; t < 8; t++) {
#pragma unroll
        for (int r = 0; r < 4; r++)
            ctile[wave][crow + r][t * 16 + ccol] = f2bf(acc[t][r]);
    }
    __syncthreads();
#pragma unroll
    for (int it = 0; it < 4; it++) {
        int rrow = it * 4 + (lane >> 4);
        int chunk = lane & 15;
        short8 vv = *(const short8*)&ctile[wave][rrow][chunk * 8];
        int gr = m0 + rrow;
        if (gr < E)
            *(short8*)(e_out + (size_t)gr * 128 + chunk * 8) = vv;
    }
}

// ---------------- aggregation: unroll-4 pipelined ----------------
__global__ __launch_bounds__(256) void agg_kernel(
    const int* __restrict__ row_ptr, const int* __restrict__ srcs,
    const float* __restrict__ q, const ushort_t* __restrict__ k,
    const ushort_t* __restrict__ v, const ushort_t* __restrict__ e,
    float* __restrict__ hout, int N)
{
    int wave = threadIdx.x >> 6;
    int lane = threadIdx.x & 63;
    int n = blockIdx.x * 4 + wave;
    if (n >= N) return;

    const float2* q2 = (const float2*)q;
    const unsigned int* k32 = (const unsigned int*)k;
    const unsigned int* v32 = (const unsigned int*)v;
    const unsigned int* e32 = (const unsigned int*)e;
    float2* h2 = (float2*)hout;

    float2 qq = q2[(size_t)n * 64 + lane];
    float2 sk = h2[(size_t)n * 64 + lane];
    float acc0 = 0.f, acc1 = 0.f, sw = 0.f;
    int jb = row_ptr[n], je = row_ptr[n + 1];

    int j = jb;
    for (; j + 4 <= je; j += 4) {
        // batch-issue all loads for 4 edges before any compute
        int s0 = srcs[j + 0];
        int s1 = srcs[j + 1];
        int s2 = srcs[j + 2];
        int s3 = srcs[j + 3];
        unsigned int ee0 = e32[(size_t)(j + 0) * 64 + lane];
        unsigned int ee1 = e32[(size_t)(j + 1) * 64 + lane];
        unsigned int ee2 = e32[(size_t)(j + 2) * 64 + lane];
        unsigned int ee3 = e32[(size_t)(j + 3) * 64 + lane];
        unsigned int ku0 = k32[(size_t)s0 * 64 + lane];
        unsigned int ku1 = k32[(size_t)s1 * 64 + lane];
        unsigned int ku2 = k32[(size_t)s2 * 64 + lane];
        unsigned int ku3 = k32[(size_t)s3 * 64 + lane];
        unsigned int vu0 = v32[(size_t)s0 * 64 + lane];
        unsigned int vu1 = v32[(size_t)s1 * 64 + lane];
        unsigned int vu2 = v32[(size_t)s2 * 64 + lane];
        unsigned int vu3 = v32[(size_t)s3 * 64 + lane];

        float p0 = qq.x * (bflo(ku0) + bflo(ee0)) + qq.y * (bfhi(ku0) + bfhi(ee0));
        float p1 = qq.x * (bflo(ku1) + bflo(ee1)) + qq.y * (bfhi(ku1) + bfhi(ee1));
        float p2 = qq.x * (bflo(ku2) + bflo(ee2)) + qq.y * (bfhi(ku2) + bfhi(ee2));
        float p3 = qq.x * (bflo(ku3) + bflo(ee3)) + qq.y * (bfhi(ku3) + bfhi(ee3));
        p0 += __shfl_xor(p0, 1); p1 += __shfl_xor(p1, 1);
        p2 += __shfl_xor(p2, 1); p3 += __shfl_xor(p3, 1);
        p0 += __shfl_xor(p0, 2); p1 += __shfl_xor(p1, 2);
        p2 += __shfl_xor(p2, 2); p3 += __shfl_xor(p3, 2);
        p0 += __shfl_xor(p0, 4); p1 += __shfl_xor(p1, 4);
        p2 += __shfl_xor(p2, 4); p3 += __shfl_xor(p3, 4);
        float w0 = __expf(p0 * 0.25f);
        float w1 = __expf(p1 * 0.25f);
        float w2 = __expf(p2 * 0.25f);
        float w3 = __expf(p3 * 0.25f);
        acc0 += w0 * (bflo(vu0) + bflo(ee0));
        acc1 += w0 * (bfhi(vu0) + bfhi(ee0));
        acc0 += w1 * (bflo(vu1) + bflo(ee1));
        acc1 += w1 * (bfhi(vu1) + bfhi(ee1));
        acc0 += w2 * (bflo(vu2) + bflo(ee2));
        acc1 += w2 * (bfhi(vu2) + bfhi(ee2));
        acc0 += w3 * (bflo(vu3) + bflo(ee3));
        acc1 += w3 * (bfhi(vu3) + bfhi(ee3));
        sw += w0 + w1 + w2 + w3;
    }
    for (; j < je; ++j) {
        int s = srcs[j];
        unsigned int ee = e32[(size_t)j * 64 + lane];
        unsigned int ku = k32[(size_t)s * 64 + lane];
        unsigned int vu = v32[(size_t)s * 64 + lane];
        float e0 = bflo(ee), e1 = bfhi(ee);
        float part = qq.x * (bflo(ku) + e0) + qq.y * (bfhi(ku) + e1);
        part += __shfl_xor(part, 1);
        part += __shfl_xor(part, 2);
        part += __shfl_xor(part, 4);
        float w = __expf(part * 0.25f);
        acc0 += w * (bflo(vu) + e0);
        acc1 += w * (bfhi(vu) + e1);
        sw += w;
    }
    float inv = 1.0f / (sw + 1e-16f);
    float2 o;
    o.x = acc0 * inv + sk.x;
    o.y = acc1 * inv + sk.y;
    h2[(size_t)n * 64 + lane] = o;
}

// ---------------- BatchNorm + ReLU ----------------
__global__ __launch_bounds__(128) void bn_stats_kernel(const float* __restrict__ h, int N,
                                                       float* __restrict__ sums) {
    int f = threadIdx.x;
    float s = 0.f, s2 = 0.f;
    for (int n = blockIdx.x; n < N; n += gridDim.x) {
        float x = h[(size_t)n * 128 + f];
        s += x;
        s2 += x * x;
    }
    atomicAdd(&sums[f], s);
    atomicAdd(&sums[128 + f], s2);
}

__global__ __launch_bounds__(256) void bn_apply_kernel(
    const float* __restrict__ h, const float* __restrict__ sums,
    const float* __restrict__ g, const float* __restrict__ be,
    float* __restrict__ out, int N)
{
    int idx = blockIdx.x * blockDim.x + threadIdx.x;
    if (idx >= N * 128) return;
    int f = idx & 127;
    float invN = 1.0f / (float)N;
    float mu = sums[f] * invN;
    float var = sums[128 + f] * invN - mu * mu;
    float x = (h[idx] - mu) * rsqrtf(var + 1e-5f) * g[f] + be[f];
    out[idx] = fmaxf(x, 0.f);
}

// ---------------------------------------------------------------------------
extern "C" void kernel_launch(void* const* d_in, const int* in_sizes, int n_in,
                              void* d_out, int out_size, void* d_ws, size_t ws_size,
                              hipStream_t stream)
{
    const float* x = (const float*)d_in[0];
    const int* edge_index = (const int*)d_in[1];
    const float* edge_attr = (const float*)d_in[2];
    int N = in_sizes[0] / 64;
    int E = in_sizes[1] / 2;
    const int* src = edge_index;
    const int* dst = edge_index + E;

    const float* W[3][9];
    for (int l = 0; l < 3; l++)
        for (int i = 0; i < 9; i++) W[l][i] = (const float*)d_in[3 + l * 9 + i];
    const float* g0 = (const float*)d_in[30];
    const float* be0 = (const float*)d_in[31];
    const float* g1 = (const float*)d_in[32];
    const float* be1 = (const float*)d_in[33];

    char* p = (char*)d_ws;
    auto alloc = [&](size_t bytes) -> char* {
        char* r = p;
        p += (bytes + 255) & ~(size_t)255;
        return r;
    };
    float* q = (float*)alloc((size_t)N * 128 * 4);
    ushort_t* k = (ushort_t*)alloc((size_t)N * 128 * 2);
    ushort_t* v = (ushort_t*)alloc((size_t)N * 128 * 2);
    float* A = (float*)alloc((size_t)N * 128 * 4);
    float* B = (float*)alloc((size_t)N * 128 * 4);
    ushort_t* e = (ushort_t*)alloc((size_t)E * 128 * 2);
    int* row_ptr = (int*)alloc((size_t)(N + 1) * 4);
    int* cursor = (int*)alloc((size_t)N * 4);
    int* histb = (int*)alloc((size_t)N * 4);
    int* eid = (int*)alloc((size_t)E * 4);
    int* srcs = (int*)alloc((size_t)E * 4);
    float* sums = (float*)alloc(256 * 4);
    ushort_t* BpackE = (ushort_t*)alloc((size_t)3 * 8192 * 2);
    ushort_t* BpackN = (ushort_t*)alloc((size_t)3 * 65536 * 2);
    float* biasc = (float*)alloc((size_t)3 * 512 * 4);

    // ---- CSR build ----
    hipMemsetAsync(histb, 0, (size_t)N * 4, stream);
    hist_kernel<<<(E + 255) / 256, 256, 0, stream>>>(dst, E, histb);
    scan_kernel<<<1, 1024, 0, stream>>>(histb, N, E, row_ptr, cursor);
    scatter_kernel<<<(E + 255) / 256, 256, 0, stream>>>(src, dst, E, cursor, eid, srcs);

    // ---- weight packing ----
    pack_We_kernel<<<(3 * 8192 + 255) / 256, 256, 0, stream>>>(W[0][6], W[1][6], W[2][6], BpackE);
    for (int l = 0; l < 3; l++) {
        int DI = (l == 0) ? 64 : 128;
        pack_Wnode_kernel<<<(DI * 512 + 255) / 256, 256, 0, stream>>>(
            W[l][0], W[l][2], W[l][4], W[l][7], DI, BpackN + (size_t)l * 65536);
        pack_bias_kernel<<<2, 256, 0, stream>>>(W[l][1], W[l][3], W[l][5], W[l][8],
                                                biasc + (size_t)l * 512);
    }

    for (int l = 0; l < 3; l++) {
        const float* hin = (l == 0) ? x : A;
        float* skipbuf = (l == 2) ? (float*)d_out : B;
        if (l == 0)
            node_gemm_mfma_kernel<64><<<(N + 63) / 64, 256, 0, stream>>>(
                hin, N, BpackN, biasc, q, k, v, skipbuf);
        else
            node_gemm_mfma_kernel<128><<<(N + 63) / 64, 256, 0, stream>>>(
                hin, N, BpackN + (size_t)l * 65536, biasc + (size_t)l * 512, q, k, v, skipbuf);
        e_gemm_mfma_kernel<<<(E + 63) / 64, 256, 0, stream>>>(
            edge_attr, eid, E, BpackE + (size_t)l * 8192, e);
        agg_kernel<<<(N + 3) / 4, 256, 0, stream>>>(row_ptr, srcs, q, k, v, e, skipbuf, N);
        if (l < 2) {
            hipMemsetAsync(sums, 0, 256 * 4, stream);
            bn_stats_kernel<<<256, 128, 0, stream>>>(skipbuf, N, sums);
            const float* gg = (l == 0) ? g0 : g1;
            const float* bb = (l == 0) ? be0 : be1;
            bn_apply_kernel<<<((size_t)N * 128 + 255) / 256, 256, 0, stream>>>(skipbuf, sums, gg, bb, A, N);
        }
    }

    // ---- second output: edge_attr passthrough ----
    hipMemcpyAsync((float*)d_out + (size_t)N * 128, edge_attr, (size_t)E * 64 * 4,
                   hipMemcpyDeviceToDevice, stream);
}

// Round 6
// 1004.052 us; speedup vs baseline: 3.4827x; 1.2331x over previous
//
#include <hip/hip_runtime.h>
#include <hip/hip_bf16.h>

typedef __attribute__((ext_vector_type(8))) short short8;
typedef __attribute__((ext_vector_type(4))) float f32x4;
typedef unsigned short ushort_t;
typedef __attribute__((ext_vector_type(2))) unsigned short ushort2v;

static __device__ __forceinline__ ushort_t f2bf(float x) {
    __hip_bfloat16 h = __float2bfloat16(x);
    return *(ushort_t*)&h;
}
static __device__ __forceinline__ float bflo(unsigned int u) { return __uint_as_float(u << 16); }
static __device__ __forceinline__ float bfhi(unsigned int u) { return __uint_as_float(u & 0xffff0000u); }
static __device__ __forceinline__ float bfu(ushort_t u) { return __uint_as_float((unsigned int)u << 16); }

// ---------------------------------------------------------------------------
// GraphTransformer: 3x TransformerConv(H=8,c=16) + BN/ReLU, fixed graph.
// CSR build once; edge_attr permuted to dst-sorted bf16 once; per layer:
// fused node GEMM (MFMA), fused aggregation (inline e=ea@We via MFMA +
// segment softmax + skip), BN+ReLU.
// ---------------------------------------------------------------------------

// ---------------- CSR build ----------------
__global__ void hist_kernel(const int* __restrict__ dst, int E, int* __restrict__ hist) {
    int i = blockIdx.x * blockDim.x + threadIdx.x;
    if (i < E) atomicAdd(&hist[dst[i]], 1);
}

__global__ __launch_bounds__(1024) void scan_kernel(const int* __restrict__ hist, int n, int total,
                                                    int* __restrict__ row_ptr, int* __restrict__ cursor) {
    __shared__ int lds[1024];
    __shared__ int s_running;
    int tid = threadIdx.x;
    if (tid == 0) s_running = 0;
    __syncthreads();
    for (int base = 0; base < n; base += 1024) {
        int i = base + tid;
        int vv = (i < n) ? hist[i] : 0;
        lds[tid] = vv;
        __syncthreads();
        for (int off = 1; off < 1024; off <<= 1) {
            int t = (tid >= off) ? lds[tid - off] : 0;
            __syncthreads();
            lds[tid] += t;
            __syncthreads();
        }
        int excl = lds[tid] - vv;
        int run = s_running;
        if (i < n) { row_ptr[i] = run + excl; cursor[i] = run + excl; }
        __syncthreads();
        if (tid == 0) s_running = run + lds[1023];
        __syncthreads();
    }
    if (tid == 0) row_ptr[n] = total;
}

__global__ void scatter_kernel(const int* __restrict__ src, const int* __restrict__ dst, int E,
                               int* __restrict__ cursor, int* __restrict__ eid, int* __restrict__ srcs) {
    int i = blockIdx.x * blockDim.x + threadIdx.x;
    if (i < E) {
        int d = dst[i];
        int pos = atomicAdd(&cursor[d], 1);
        eid[pos] = i;
        srcs[pos] = src[i];
    }
}

// ---------------- edge_attr permute to dst-sorted order, bf16 ----------------
__global__ __launch_bounds__(256) void permute_ea_kernel(
    const float* __restrict__ edge_attr, const int* __restrict__ eid, int E,
    ushort_t* __restrict__ ea)
{
    int idx = blockIdx.x * blockDim.x + threadIdx.x;
    if (idx >= E * 8) return;
    int j = idx >> 3, seg = idx & 7;
    int rsrc = eid[j];
    const float* s = edge_attr + (size_t)rsrc * 64 + seg * 8;
    float4 f0 = *(const float4*)s;
    float4 f1 = *(const float4*)(s + 4);
    short8 o;
    o[0] = f2bf(f0.x); o[1] = f2bf(f0.y); o[2] = f2bf(f0.z); o[3] = f2bf(f0.w);
    o[4] = f2bf(f1.x); o[5] = f2bf(f1.y); o[6] = f2bf(f1.z); o[7] = f2bf(f1.w);
    *(short8*)(ea + (size_t)j * 64 + seg * 8) = o;
}

// ---------------- weight packing ----------------
__global__ __launch_bounds__(256) void pack_Wnode_kernel(
    const float* __restrict__ Wq, const float* __restrict__ Wk,
    const float* __restrict__ Wv, const float* __restrict__ Ws,
    int DI, ushort_t* __restrict__ dst)
{
    int NKF = DI >> 5;
    int total = DI * 512;
    int idx = blockIdx.x * blockDim.x + threadIdx.x;
    if (idx >= total) return;
    int j = idx & 7;
    int lane = (idx >> 3) & 63;
    int rest = idx >> 9;
    int kf = rest % NKF;
    int t = rest / NKF;
    int kdim = kf * 32 + (lane >> 4) * 8 + j;
    int ncol = t * 16 + (lane & 15);
    const float* W = (ncol < 128) ? Wq : (ncol < 256) ? Wk : (ncol < 384) ? Wv : Ws;
    dst[idx] = f2bf(W[kdim * 128 + (ncol & 127)]);
}

__global__ __launch_bounds__(256) void pack_bias_kernel(
    const float* __restrict__ bq, const float* __restrict__ bk,
    const float* __restrict__ bv, const float* __restrict__ bs,
    float* __restrict__ dst)
{
    int i = threadIdx.x + blockIdx.x * blockDim.x;
    if (i >= 512) return;
    const float* b = (i < 128) ? bq : (i < 256) ? bk : (i < 384) ? bv : bs;
    dst[i] = b[i & 127];
}

__global__ __launch_bounds__(256) void pack_We_kernel(
    const float* __restrict__ We0, const float* __restrict__ We1,
    const float* __restrict__ We2, ushort_t* __restrict__ Bpack)
{
    int idx = blockIdx.x * blockDim.x + threadIdx.x;
    if (idx >= 3 * 8192) return;
    int j = idx & 7;
    int lane = (idx >> 3) & 63;
    int kk = (idx >> 9) & 1;
    int t = (idx >> 10) & 7;
    int layer = idx >> 13;
    const float* We = (layer == 0) ? We0 : (layer == 1) ? We1 : We2;
    int kdim = kk * 32 + (lane >> 4) * 8 + j;
    int ncol = t * 16 + (lane & 15);
    Bpack[idx] = f2bf(We[kdim * 128 + ncol]);
}

// ---------------- fused node GEMM via MFMA ----------------
template <int DI>
__global__ __launch_bounds__(256) void node_gemm_mfma_kernel(
    const float* __restrict__ hin, int N,
    const ushort_t* __restrict__ Bpack, const float* __restrict__ biasc,
    float* __restrict__ qout, ushort_t* __restrict__ kout,
    ushort_t* __restrict__ vout, float* __restrict__ skipout)
{
    constexpr int NKF = DI / 32;
    __shared__ float ctile[64][132];
    int wave = threadIdx.x >> 6;
    int lane = threadIdx.x & 63;
    int tid = threadIdx.x;
    int base = blockIdx.x * 64;
    int m0 = base + wave * 16;

    int mrow = min(m0 + (lane & 15), N - 1);
    const float* arow = hin + (size_t)mrow * DI;
    int koff = (lane >> 4) * 8;

    short8 a[NKF];
#pragma unroll
    for (int kf = 0; kf < NKF; kf++) {
        float4 fa = *(const float4*)(arow + kf * 32 + koff);
        float4 fb = *(const float4*)(arow + kf * 32 + koff + 4);
        short8 t;
        t[0] = f2bf(fa.x); t[1] = f2bf(fa.y); t[2] = f2bf(fa.z); t[3] = f2bf(fa.w);
        t[4] = f2bf(fb.x); t[5] = f2bf(fb.y); t[6] = f2bf(fb.z); t[7] = f2bf(fb.w);
        a[kf] = t;
    }

    const short8* Bp = (const short8*)Bpack;
    f32x4 acc[32];
#pragma unroll
    for (int t = 0; t < 32; t++) acc[t] = (f32x4){0.f, 0.f, 0.f, 0.f};
#pragma unroll
    for (int t = 0; t < 32; t++) {
#pragma unroll
        for (int kf = 0; kf < NKF; kf++)
            acc[t] = __builtin_amdgcn_mfma_f32_16x16x32_bf16(a[kf], Bp[(t * NKF + kf) * 64 + lane], acc[t], 0, 0, 0);
    }

    int crow = (lane >> 4) * 4;
    int ccol = lane & 15;
#pragma unroll
    for (int osel = 0; osel < 4; osel++) {
#pragma unroll
        for (int t8 = 0; t8 < 8; t8++) {
            float bb = biasc[osel * 128 + t8 * 16 + ccol];
#pragma unroll
            for (int r = 0; r < 4; r++)
                ctile[wave * 16 + crow + r][t8 * 16 + ccol] = acc[osel * 8 + t8][r] + bb;
        }
        __syncthreads();
        if (osel == 0 || osel == 3) {
            float* out = (osel == 0) ? qout : skipout;
#pragma unroll
            for (int it = 0; it < 8; it++) {
                int idx4 = it * 256 + tid;
                int row = idx4 >> 5;
                int c4 = idx4 & 31;
                int gr = base + row;
                if (gr < N) {
                    float4 vv = *(const float4*)&ctile[row][c4 * 4];
                    *(float4*)(out + (size_t)gr * 128 + c4 * 4) = vv;
                }
            }
        } else {
            ushort_t* out = (osel == 1) ? kout : vout;
#pragma unroll
            for (int it = 0; it < 4; it++) {
                int idx8 = it * 256 + tid;
                int row = idx8 >> 4;
                int c8 = idx8 & 15;
                int gr = base + row;
                if (gr < N) {
                    const float* s = &ctile[row][c8 * 8];
                    short8 vv;
#pragma unroll
                    for (int jj = 0; jj < 8; jj++) vv[jj] = f2bf(s[jj]);
                    *(short8*)(out + (size_t)gr * 128 + c8 * 8) = vv;
                }
            }
        }
        __syncthreads();
    }
}

// ---------------- fused aggregation: inline e-MFMA + segment softmax + skip --
__global__ __launch_bounds__(256) void agg_fused_kernel(
    const int* __restrict__ row_ptr, const int* __restrict__ srcs,
    const float* __restrict__ q, const ushort_t* __restrict__ k,
    const ushort_t* __restrict__ v, const ushort_t* __restrict__ ea,
    const ushort_t* __restrict__ BpackWe,
    float* __restrict__ hout, int N)
{
    __shared__ ushort_t bsh[8192];            // We fragments, 16 KB
    __shared__ ushort_t elds[4][16][136];     // per-wave e tile, +pad
    int tid = threadIdx.x;
    {
        const short8* s8 = (const short8*)BpackWe;
        short8* d8 = (short8*)bsh;
#pragma unroll
        for (int i = 0; i < 4; i++) d8[i * 256 + tid] = s8[i * 256 + tid];
    }
    __syncthreads();

    int wave = tid >> 6, lane = tid & 63;
    int n = blockIdx.x * 4 + wave;
    if (n >= N) return;

    const float2* q2 = (const float2*)q;
    const unsigned int* k32 = (const unsigned int*)k;
    const unsigned int* v32 = (const unsigned int*)v;
    float2* h2 = (float2*)hout;
    const short8* bs8 = (const short8*)bsh;

    int ch = lane & 15, kg = lane >> 4;
    float2 qq = q2[(size_t)n * 64 + lane];
    float2 sk = h2[(size_t)n * 64 + lane];
    float acc0 = 0.f, acc1 = 0.f, sw = 0.f;
    int jb = row_ptr[n], je = row_ptr[n + 1];

    for (int c0 = jb; c0 < je; c0 += 16) {
        int jl = min(c0 + ch, je - 1);
        int sv = srcs[jl];                        // lane r<16 holds srcs[c0+r]
        const ushort_t* arow = ea + (size_t)jl * 64;
        short8 a0 = *(const short8*)(arow + kg * 8);
        short8 a1 = *(const short8*)(arow + 32 + kg * 8);

        // e_tile[16 edges][128 ch] = A @ We  (C layout: row=kg*4+r, col=t*16+ch)
#pragma unroll
        for (int t = 0; t < 8; t++) {
            f32x4 z = (f32x4){0.f, 0.f, 0.f, 0.f};
            z = __builtin_amdgcn_mfma_f32_16x16x32_bf16(a0, bs8[(t * 2 + 0) * 64 + lane], z, 0, 0, 0);
            z = __builtin_amdgcn_mfma_f32_16x16x32_bf16(a1, bs8[(t * 2 + 1) * 64 + lane], z, 0, 0, 0);
#pragma unroll
            for (int r = 0; r < 4; r++)
                elds[wave][kg * 4 + r][t * 16 + ch] = f2bf(z[r]);
        }
        // compiler fence: elds writes (ushort) must not be reordered past the
        // reads below; HW DS pipe is in-order per wave.
        asm volatile("" ::: "memory");

        int cnt = min(16, je - c0);
        int r = 0;
        for (; r + 4 <= cnt; r += 4) {
            int s0 = __shfl(sv, r + 0);
            int s1 = __shfl(sv, r + 1);
            int s2 = __shfl(sv, r + 2);
            int s3 = __shfl(sv, r + 3);
            ushort2v ee0 = *(const ushort2v*)&elds[wave][r + 0][2 * lane];
            ushort2v ee1 = *(const ushort2v*)&elds[wave][r + 1][2 * lane];
            ushort2v ee2 = *(const ushort2v*)&elds[wave][r + 2][2 * lane];
            ushort2v ee3 = *(const ushort2v*)&elds[wave][r + 3][2 * lane];
            unsigned int ku0 = k32[(size_t)s0 * 64 + lane];
            unsigned int ku1 = k32[(size_t)s1 * 64 + lane];
            unsigned int ku2 = k32[(size_t)s2 * 64 + lane];
            unsigned int ku3 = k32[(size_t)s3 * 64 + lane];
            unsigned int vu0 = v32[(size_t)s0 * 64 + lane];
            unsigned int vu1 = v32[(size_t)s1 * 64 + lane];
            unsigned int vu2 = v32[(size_t)s2 * 64 + lane];
            unsigned int vu3 = v32[(size_t)s3 * 64 + lane];

            float e0a = bfu(ee0[0]), e0b = bfu(ee0[1]);
            float e1a = bfu(ee1[0]), e1b = bfu(ee1[1]);
            float e2a = bfu(ee2[0]), e2b = bfu(ee2[1]);
            float e3a = bfu(ee3[0]), e3b = bfu(ee3[1]);
            float p0 = qq.x * (bflo(ku0) + e0a) + qq.y * (bfhi(ku0) + e0b);
            float p1 = qq.x * (bflo(ku1) + e1a) + qq.y * (bfhi(ku1) + e1b);
            float p2 = qq.x * (bflo(ku2) + e2a) + qq.y * (bfhi(ku2) + e2b);
            float p3 = qq.x * (bflo(ku3) + e3a) + qq.y * (bfhi(ku3) + e3b);
            p0 += __shfl_xor(p0, 1); p1 += __shfl_xor(p1, 1);
            p2 += __shfl_xor(p2, 1); p3 += __shfl_xor(p3, 1);
            p0 += __shfl_xor(p0, 2); p1 += __shfl_xor(p1, 2);
            p2 += __shfl_xor(p2, 2); p3 += __shfl_xor(p3, 2);
            p0 += __shfl_xor(p0, 4); p1 += __shfl_xor(p1, 4);
            p2 += __shfl_xor(p2, 4); p3 += __shfl_xor(p3, 4);
            float w0 = __expf(fminf(p0 * 0.25f, 60.0f));
            float w1 = __expf(fminf(p1 * 0.25f, 60.0f));
            float w2 = __expf(fminf(p2 * 0.25f, 60.0f));
            float w3 = __expf(fminf(p3 * 0.25f, 60.0f));
            acc0 += w0 * (bflo(vu0) + e0a);
            acc1 += w0 * (bfhi(vu0) + e0b);
            acc0 += w1 * (bflo(vu1) + e1a);
            acc1 += w1 * (bfhi(vu1) + e1b);
            acc0 += w2 * (bflo(vu2) + e2a);
            acc1 += w2 * (bfhi(vu2) + e2b);
            acc0 += w3 * (bflo(vu3) + e3a);
            acc1 += w3 * (bfhi(vu3) + e3b);
            sw += w0 + w1 + w2 + w3;
        }
        for (; r < cnt; ++r) {
            int s = __shfl(sv, r);
            ushort2v ee = *(const ushort2v*)&elds[wave][r][2 * lane];
            unsigned int ku = k32[(size_t)s * 64 + lane];
            unsigned int vu = v32[(size_t)s * 64 + lane];
            float e0 = bfu(ee[0]), e1 = bfu(ee[1]);
            float part = qq.x * (bflo(ku) + e0) + qq.y * (bfhi(ku) + e1);
            part += __shfl_xor(part, 1);
            part += __shfl_xor(part, 2);
            part += __shfl_xor(part, 4);
            float w = __expf(fminf(part * 0.25f, 60.0f));
            acc0 += w * (bflo(vu) + e0);
            acc1 += w * (bfhi(vu) + e1);
            sw += w;
        }
    }
    float inv = 1.0f / (sw + 1e-16f);
    float2 o;
    o.x = acc0 * inv + sk.x;
    o.y = acc1 * inv + sk.y;
    h2[(size_t)n * 64 + lane] = o;
}

// ---------------- BatchNorm + ReLU ----------------
__global__ __launch_bounds__(128) void bn_stats_kernel(const float* __restrict__ h, int N,
                                                       float* __restrict__ sums) {
    int f = threadIdx.x;
    float s = 0.f, s2 = 0.f;
    for (int n = blockIdx.x; n < N; n += gridDim.x) {
        float x = h[(size_t)n * 128 + f];
        s += x;
        s2 += x * x;
    }
    atomicAdd(&sums[f], s);
    atomicAdd(&sums[128 + f], s2);
}

__global__ __launch_bounds__(256) void bn_apply_kernel(
    const float* __restrict__ h, const float* __restrict__ sums,
    const float* __restrict__ g, const float* __restrict__ be,
    float* __restrict__ out, int N)
{
    int idx = blockIdx.x * blockDim.x + threadIdx.x;
    if (idx >= N * 128) return;
    int f = idx & 127;
    float invN = 1.0f / (float)N;
    float mu = sums[f] * invN;
    float var = sums[128 + f] * invN - mu * mu;
    float x = (h[idx] - mu) * rsqrtf(var + 1e-5f) * g[f] + be[f];
    out[idx] = fmaxf(x, 0.f);
}

// ---------------------------------------------------------------------------
extern "C" void kernel_launch(void* const* d_in, const int* in_sizes, int n_in,
                              void* d_out, int out_size, void* d_ws, size_t ws_size,
                              hipStream_t stream)
{
    const float* x = (const float*)d_in[0];
    const int* edge_index = (const int*)d_in[1];
    const float* edge_attr = (const float*)d_in[2];
    int N = in_sizes[0] / 64;
    int E = in_sizes[1] / 2;
    const int* src = edge_index;
    const int* dst = edge_index + E;

    const float* W[3][9];
    for (int l = 0; l < 3; l++)
        for (int i = 0; i < 9; i++) W[l][i] = (const float*)d_in[3 + l * 9 + i];
    const float* g0 = (const float*)d_in[30];
    const float* be0 = (const float*)d_in[31];
    const float* g1 = (const float*)d_in[32];
    const float* be1 = (const float*)d_in[33];

    char* p = (char*)d_ws;
    auto alloc = [&](size_t bytes) -> char* {
        char* r = p;
        p += (bytes + 255) & ~(size_t)255;
        return r;
    };
    float* q = (float*)alloc((size_t)N * 128 * 4);
    ushort_t* k = (ushort_t*)alloc((size_t)N * 128 * 2);
    ushort_t* v = (ushort_t*)alloc((size_t)N * 128 * 2);
    float* A = (float*)alloc((size_t)N * 128 * 4);
    float* B = (float*)alloc((size_t)N * 128 * 4);
    ushort_t* ea = (ushort_t*)alloc((size_t)E * 64 * 2);
    int* row_ptr = (int*)alloc((size_t)(N + 1) * 4);
    int* cursor = (int*)alloc((size_t)N * 4);
    int* histb = (int*)alloc((size_t)N * 4);
    int* eid = (int*)alloc((size_t)E * 4);
    int* srcs = (int*)alloc((size_t)E * 4);
    float* sums = (float*)alloc(256 * 4);
    ushort_t* BpackE = (ushort_t*)alloc((size_t)3 * 8192 * 2);
    ushort_t* BpackN = (ushort_t*)alloc((size_t)3 * 65536 * 2);
    float* biasc = (float*)alloc((size_t)3 * 512 * 4);

    // ---- CSR build ----
    hipMemsetAsync(histb, 0, (size_t)N * 4, stream);
    hist_kernel<<<(E + 255) / 256, 256, 0, stream>>>(dst, E, histb);
    scan_kernel<<<1, 1024, 0, stream>>>(histb, N, E, row_ptr, cursor);
    scatter_kernel<<<(E + 255) / 256, 256, 0, stream>>>(src, dst, E, cursor, eid, srcs);
    permute_ea_kernel<<<(E * 8 + 255) / 256, 256, 0, stream>>>(edge_attr, eid, E, ea);

    // ---- weight packing ----
    pack_We_kernel<<<(3 * 8192 + 255) / 256, 256, 0, stream>>>(W[0][6], W[1][6], W[2][6], BpackE);
    for (int l = 0; l < 3; l++) {
        int DI = (l == 0) ? 64 : 128;
        pack_Wnode_kernel<<<(DI * 512 + 255) / 256, 256, 0, stream>>>(
            W[l][0], W[l][2], W[l][4], W[l][7], DI, BpackN + (size_t)l * 65536);
        pack_bias_kernel<<<2, 256, 0, stream>>>(W[l][1], W[l][3], W[l][5], W[l][8],
                                                biasc + (size_t)l * 512);
    }

    for (int l = 0; l < 3; l++) {
        const float* hin = (l == 0) ? x : A;
        float* skipbuf = (l == 2) ? (float*)d_out : B;
        if (l == 0)
            node_gemm_mfma_kernel<64><<<(N + 63) / 64, 256, 0, stream>>>(
                hin, N, BpackN, biasc, q, k, v, skipbuf);
        else
            node_gemm_mfma_kernel<128><<<(N + 63) / 64, 256, 0, stream>>>(
                hin, N, BpackN + (size_t)l * 65536, biasc + (size_t)l * 512, q, k, v, skipbuf);
        agg_fused_kernel<<<(N + 3) / 4, 256, 0, stream>>>(
            row_ptr, srcs, q, k, v, ea, BpackE + (size_t)l * 8192, skipbuf, N);
        if (l < 2) {
            hipMemsetAsync(sums, 0, 256 * 4, stream);
            bn_stats_kernel<<<256, 128, 0, stream>>>(skipbuf, N, sums);
            const float* gg = (l == 0) ? g0 : g1;
            const float* bb = (l == 0) ? be0 : be1;
            bn_apply_kernel<<<((size_t)N * 128 + 255) / 256, 256, 0, stream>>>(skipbuf, sums, gg, bb, A, N);
        }
    }

    // ---- second output: edge_attr passthrough ----
    hipMemcpyAsync((float*)d_out + (size_t)N * 128, edge_attr, (size_t)E * 64 * 4,
                   hipMemcpyDeviceToDevice, stream);
}

// Round 7
// 772.052 us; speedup vs baseline: 4.5292x; 1.3005x over previous
//
#include <hip/hip_runtime.h>
#include <hip/hip_bf16.h>

typedef __attribute__((ext_vector_type(8))) short short8;
typedef __attribute__((ext_vector_type(4))) float f32x4;
typedef unsigned short ushort_t;
typedef __attribute__((ext_vector_type(2))) unsigned short ushort2v;

static __device__ __forceinline__ ushort_t f2bf(float x) {
    __hip_bfloat16 h = __float2bfloat16(x);
    return *(ushort_t*)&h;
}
static __device__ __forceinline__ float bflo(unsigned int u) { return __uint_as_float(u << 16); }
static __device__ __forceinline__ float bfhi(unsigned int u) { return __uint_as_float(u & 0xffff0000u); }
static __device__ __forceinline__ float bfu(ushort_t u) { return __uint_as_float((unsigned int)u << 16); }

// ---------------------------------------------------------------------------
// GraphTransformer: 3x TransformerConv(H=8,c=16) + BN/ReLU, fixed graph.
// CSR build (parallel scan); edge_attr permuted to dst-sorted bf16 once;
// per layer: fused node GEMM (MFMA, BN+ReLU of previous layer applied inline),
// fused aggregation (inline e=ea@We MFMA + segment softmax + skip), BN stats.
// ---------------------------------------------------------------------------

// ---------------- CSR build ----------------
__global__ void hist_kernel(const int* __restrict__ dst, int E, int* __restrict__ hist) {
    int i = blockIdx.x * blockDim.x + threadIdx.x;
    if (i < E) atomicAdd(&hist[dst[i]], 1);
}

// per-block (1024) exclusive scan; excl -> row_ptr[i], block total -> bsums
__global__ __launch_bounds__(1024) void scan_block_kernel(
    const int* __restrict__ hist, int n, int* __restrict__ row_ptr, int* __restrict__ bsums)
{
    __shared__ int lds[1024];
    int tid = threadIdx.x;
    int i = blockIdx.x * 1024 + tid;
    int vv = (i < n) ? hist[i] : 0;
    lds[tid] = vv;
    __syncthreads();
    for (int off = 1; off < 1024; off <<= 1) {
        int t = (tid >= off) ? lds[tid - off] : 0;
        __syncthreads();
        lds[tid] += t;
        __syncthreads();
    }
    if (i < n) row_ptr[i] = lds[tid] - vv;
    if (tid == 1023) bsums[blockIdx.x] = lds[1023];
}

__global__ void scan_tops_kernel(int* __restrict__ bsums, int nb) {
    if (threadIdx.x == 0 && blockIdx.x == 0) {
        int run = 0;
        for (int i = 0; i < nb; i++) { int t = bsums[i]; bsums[i] = run; run += t; }
    }
}

__global__ __launch_bounds__(256) void scan_add_kernel(
    const int* __restrict__ bsums, int n, int total,
    int* __restrict__ row_ptr, int* __restrict__ cursor)
{
    int i = blockIdx.x * blockDim.x + threadIdx.x;
    if (i < n) {
        int vv = row_ptr[i] + bsums[i >> 10];
        row_ptr[i] = vv;
        cursor[i] = vv;
    }
    if (i == 0) row_ptr[n] = total;
}

__global__ void scatter_kernel(const int* __restrict__ src, const int* __restrict__ dst, int E,
                               int* __restrict__ cursor, int* __restrict__ eid, int* __restrict__ srcs) {
    int i = blockIdx.x * blockDim.x + threadIdx.x;
    if (i < E) {
        int d = dst[i];
        int pos = atomicAdd(&cursor[d], 1);
        eid[pos] = i;
        srcs[pos] = src[i];
    }
}

// ---------------- edge_attr permute to dst-sorted order, bf16 ----------------
__global__ __launch_bounds__(256) void permute_ea_kernel(
    const float* __restrict__ edge_attr, const int* __restrict__ eid, int E,
    ushort_t* __restrict__ ea)
{
    int idx = blockIdx.x * blockDim.x + threadIdx.x;
    if (idx >= E * 8) return;
    int j = idx >> 3, seg = idx & 7;
    int rsrc = eid[j];
    const float* s = edge_attr + (size_t)rsrc * 64 + seg * 8;
    float4 f0 = *(const float4*)s;
    float4 f1 = *(const float4*)(s + 4);
    short8 o;
    o[0] = f2bf(f0.x); o[1] = f2bf(f0.y); o[2] = f2bf(f0.z); o[3] = f2bf(f0.w);
    o[4] = f2bf(f1.x); o[5] = f2bf(f1.y); o[6] = f2bf(f1.z); o[7] = f2bf(f1.w);
    *(short8*)(ea + (size_t)j * 64 + seg * 8) = o;
}

// ---------------- weight packing ----------------
__global__ __launch_bounds__(256) void pack_Wnode_kernel(
    const float* __restrict__ Wq, const float* __restrict__ Wk,
    const float* __restrict__ Wv, const float* __restrict__ Ws,
    int DI, ushort_t* __restrict__ dst)
{
    int NKF = DI >> 5;
    int total = DI * 512;
    int idx = blockIdx.x * blockDim.x + threadIdx.x;
    if (idx >= total) return;
    int j = idx & 7;
    int lane = (idx >> 3) & 63;
    int rest = idx >> 9;
    int kf = rest % NKF;
    int t = rest / NKF;
    int kdim = kf * 32 + (lane >> 4) * 8 + j;
    int ncol = t * 16 + (lane & 15);
    const float* W = (ncol < 128) ? Wq : (ncol < 256) ? Wk : (ncol < 384) ? Wv : Ws;
    dst[idx] = f2bf(W[kdim * 128 + (ncol & 127)]);
}

__global__ __launch_bounds__(256) void pack_bias_kernel(
    const float* __restrict__ bq, const float* __restrict__ bk,
    const float* __restrict__ bv, const float* __restrict__ bs,
    float* __restrict__ dst)
{
    int i = threadIdx.x + blockIdx.x * blockDim.x;
    if (i >= 512) return;
    const float* b = (i < 128) ? bq : (i < 256) ? bk : (i < 384) ? bv : bs;
    dst[i] = b[i & 127];
}

__global__ __launch_bounds__(256) void pack_We_kernel(
    const float* __restrict__ We0, const float* __restrict__ We1,
    const float* __restrict__ We2, ushort_t* __restrict__ Bpack)
{
    int idx = blockIdx.x * blockDim.x + threadIdx.x;
    if (idx >= 3 * 8192) return;
    int j = idx & 7;
    int lane = (idx >> 3) & 63;
    int kk = (idx >> 9) & 1;
    int t = (idx >> 10) & 7;
    int layer = idx >> 13;
    const float* We = (layer == 0) ? We0 : (layer == 1) ? We1 : We2;
    int kdim = kk * 32 + (lane >> 4) * 8 + j;
    int ncol = t * 16 + (lane & 15);
    Bpack[idx] = f2bf(We[kdim * 128 + ncol]);
}

// ---------------- fused node GEMM via MFMA (+ inline BN/ReLU of input) ------
template <int DI, bool BN>
__global__ __launch_bounds__(256) void node_gemm_mfma_kernel(
    const float* __restrict__ hin, int N,
    const ushort_t* __restrict__ Bpack, const float* __restrict__ biasc,
    const float* __restrict__ scale, const float* __restrict__ shift,
    float* __restrict__ qout, ushort_t* __restrict__ kout,
    ushort_t* __restrict__ vout, float* __restrict__ skipout)
{
    constexpr int NKF = DI / 32;
    __shared__ float ctile[64][132];
    int wave = threadIdx.x >> 6;
    int lane = threadIdx.x & 63;
    int tid = threadIdx.x;
    int base = blockIdx.x * 64;
    int m0 = base + wave * 16;

    int mrow = min(m0 + (lane & 15), N - 1);
    const float* arow = hin + (size_t)mrow * DI;
    int koff = (lane >> 4) * 8;

    short8 a[NKF];
#pragma unroll
    for (int kf = 0; kf < NKF; kf++) {
        float4 fa = *(const float4*)(arow + kf * 32 + koff);
        float4 fb = *(const float4*)(arow + kf * 32 + koff + 4);
        if constexpr (BN) {
            int c0 = kf * 32 + koff;
            float4 sa = *(const float4*)(scale + c0);
            float4 sb = *(const float4*)(scale + c0 + 4);
            float4 ha = *(const float4*)(shift + c0);
            float4 hb = *(const float4*)(shift + c0 + 4);
            fa.x = fmaxf(fa.x * sa.x + ha.x, 0.f);
            fa.y = fmaxf(fa.y * sa.y + ha.y, 0.f);
            fa.z = fmaxf(fa.z * sa.z + ha.z, 0.f);
            fa.w = fmaxf(fa.w * sa.w + ha.w, 0.f);
            fb.x = fmaxf(fb.x * sb.x + hb.x, 0.f);
            fb.y = fmaxf(fb.y * sb.y + hb.y, 0.f);
            fb.z = fmaxf(fb.z * sb.z + hb.z, 0.f);
            fb.w = fmaxf(fb.w * sb.w + hb.w, 0.f);
        }
        short8 t;
        t[0] = f2bf(fa.x); t[1] = f2bf(fa.y); t[2] = f2bf(fa.z); t[3] = f2bf(fa.w);
        t[4] = f2bf(fb.x); t[5] = f2bf(fb.y); t[6] = f2bf(fb.z); t[7] = f2bf(fb.w);
        a[kf] = t;
    }

    const short8* Bp = (const short8*)Bpack;
    f32x4 acc[32];
#pragma unroll
    for (int t = 0; t < 32; t++) acc[t] = (f32x4){0.f, 0.f, 0.f, 0.f};
#pragma unroll
    for (int t = 0; t < 32; t++) {
#pragma unroll
        for (int kf = 0; kf < NKF; kf++)
            acc[t] = __builtin_amdgcn_mfma_f32_16x16x32_bf16(a[kf], Bp[(t * NKF + kf) * 64 + lane], acc[t], 0, 0, 0);
    }

    int crow = (lane >> 4) * 4;
    int ccol = lane & 15;
#pragma unroll
    for (int osel = 0; osel < 4; osel++) {
#pragma unroll
        for (int t8 = 0; t8 < 8; t8++) {
            float bb = biasc[osel * 128 + t8 * 16 + ccol];
#pragma unroll
            for (int r = 0; r < 4; r++)
                ctile[wave * 16 + crow + r][t8 * 16 + ccol] = acc[osel * 8 + t8][r] + bb;
        }
        __syncthreads();
        if (osel == 0 || osel == 3) {
            float* out = (osel == 0) ? qout : skipout;
#pragma unroll
            for (int it = 0; it < 8; it++) {
                int idx4 = it * 256 + tid;
                int row = idx4 >> 5;
                int c4 = idx4 & 31;
                int gr = base + row;
                if (gr < N) {
                    float4 vv = *(const float4*)&ctile[row][c4 * 4];
                    *(float4*)(out + (size_t)gr * 128 + c4 * 4) = vv;
                }
            }
        } else {
            ushort_t* out = (osel == 1) ? kout : vout;
#pragma unroll
            for (int it = 0; it < 4; it++) {
                int idx8 = it * 256 + tid;
                int row = idx8 >> 4;
                int c8 = idx8 & 15;
                int gr = base + row;
                if (gr < N) {
                    const float* s = &ctile[row][c8 * 8];
                    short8 vv;
#pragma unroll
                    for (int jj = 0; jj < 8; jj++) vv[jj] = f2bf(s[jj]);
                    *(short8*)(out + (size_t)gr * 128 + c8 * 8) = vv;
                }
            }
        }
        __syncthreads();
    }
}

// ---------------- fused aggregation: inline e-MFMA + segment softmax + skip --
__global__ __launch_bounds__(256) void agg_fused_kernel(
    const int* __restrict__ row_ptr, const int* __restrict__ srcs,
    const float* __restrict__ q, const ushort_t* __restrict__ k,
    const ushort_t* __restrict__ v, const ushort_t* __restrict__ ea,
    const ushort_t* __restrict__ BpackWe,
    float* __restrict__ hout, int N)
{
    __shared__ ushort_t bsh[8192];            // We fragments, 16 KB
    __shared__ ushort_t elds[4][16][136];     // per-wave e tile, +pad
    int tid = threadIdx.x;
    {
        const short8* s8 = (const short8*)BpackWe;
        short8* d8 = (short8*)bsh;
#pragma unroll
        for (int i = 0; i < 4; i++) d8[i * 256 + tid] = s8[i * 256 + tid];
    }
    __syncthreads();

    int wave = tid >> 6, lane = tid & 63;
    int n = blockIdx.x * 4 + wave;
    if (n >= N) return;

    const float2* q2 = (const float2*)q;
    const unsigned int* k32 = (const unsigned int*)k;
    const unsigned int* v32 = (const unsigned int*)v;
    float2* h2 = (float2*)hout;
    const short8* bs8 = (const short8*)bsh;

    int ch = lane & 15, kg = lane >> 4;
    float2 qq = q2[(size_t)n * 64 + lane];
    float2 sk = h2[(size_t)n * 64 + lane];
    float acc0 = 0.f, acc1 = 0.f, sw = 0.f;
    int jb = row_ptr[n], je = row_ptr[n + 1];

    short8 a0 = {}, a1 = {};
    int sv = 0;
    if (jb < je) {
        int j0 = min(jb + ch, je - 1);
        sv = srcs[j0];
        const ushort_t* row0 = ea + (size_t)j0 * 64;
        a0 = *(const short8*)(row0 + kg * 8);
        a1 = *(const short8*)(row0 + 32 + kg * 8);
    }

    for (int c0 = jb; c0 < je; c0 += 16) {
        // e_tile[16 edges][128 ch] = A @ We  (C layout: row=kg*4+r, col=t*16+ch)
#pragma unroll
        for (int t = 0; t < 8; t++) {
            f32x4 z = (f32x4){0.f, 0.f, 0.f, 0.f};
            z = __builtin_amdgcn_mfma_f32_16x16x32_bf16(a0, bs8[(t * 2 + 0) * 64 + lane], z, 0, 0, 0);
            z = __builtin_amdgcn_mfma_f32_16x16x32_bf16(a1, bs8[(t * 2 + 1) * 64 + lane], z, 0, 0, 0);
#pragma unroll
            for (int r = 0; r < 4; r++)
                elds[wave][kg * 4 + r][t * 16 + ch] = f2bf(z[r]);
        }

        // prefetch next chunk's fragments + srcs (issued before the fence so
        // their latency hides under the softmax loop below)
        int cn = c0 + 16;
        short8 na0 = a0, na1 = a1;
        int nsv = sv;
        if (cn < je) {
            int jn = min(cn + ch, je - 1);
            nsv = srcs[jn];
            const ushort_t* nrow = ea + (size_t)jn * 64;
            na0 = *(const short8*)(nrow + kg * 8);
            na1 = *(const short8*)(nrow + 32 + kg * 8);
        }

        // compiler fence: elds writes must not be reordered past the reads
        // below; HW DS pipe is in-order per wave.
        asm volatile("" ::: "memory");

        int cnt = min(16, je - c0);
        int r = 0;
        for (; r + 8 <= cnt; r += 8) {
            int s[8];
            ushort2v ee[8];
            unsigned int ku[8], vu[8];
#pragma unroll
            for (int u = 0; u < 8; u++) s[u] = __shfl(sv, r + u);
#pragma unroll
            for (int u = 0; u < 8; u++) ee[u] = *(const ushort2v*)&elds[wave][r + u][2 * lane];
#pragma unroll
            for (int u = 0; u < 8; u++) ku[u] = k32[(size_t)s[u] * 64 + lane];
#pragma unroll
            for (int u = 0; u < 8; u++) vu[u] = v32[(size_t)s[u] * 64 + lane];
            float p[8];
#pragma unroll
            for (int u = 0; u < 8; u++)
                p[u] = qq.x * (bflo(ku[u]) + bfu(ee[u][0])) + qq.y * (bfhi(ku[u]) + bfu(ee[u][1]));
#pragma unroll
            for (int u = 0; u < 8; u++) {
                p[u] += __shfl_xor(p[u], 1);
                p[u] += __shfl_xor(p[u], 2);
                p[u] += __shfl_xor(p[u], 4);
            }
            float w[8];
#pragma unroll
            for (int u = 0; u < 8; u++) w[u] = __expf(fminf(p[u] * 0.25f, 60.0f));
#pragma unroll
            for (int u = 0; u < 8; u++) {
                acc0 += w[u] * (bflo(vu[u]) + bfu(ee[u][0]));
                acc1 += w[u] * (bfhi(vu[u]) + bfu(ee[u][1]));
                sw += w[u];
            }
        }
        for (; r + 4 <= cnt; r += 4) {
            int s[4];
            ushort2v ee[4];
            unsigned int ku[4], vu[4];
#pragma unroll
            for (int u = 0; u < 4; u++) s[u] = __shfl(sv, r + u);
#pragma unroll
            for (int u = 0; u < 4; u++) ee[u] = *(const ushort2v*)&elds[wave][r + u][2 * lane];
#pragma unroll
            for (int u = 0; u < 4; u++) ku[u] = k32[(size_t)s[u] * 64 + lane];
#pragma unroll
            for (int u = 0; u < 4; u++) vu[u] = v32[(size_t)s[u] * 64 + lane];
            float p[4];
#pragma unroll
            for (int u = 0; u < 4; u++)
                p[u] = qq.x * (bflo(ku[u]) + bfu(ee[u][0])) + qq.y * (bfhi(ku[u]) + bfu(ee[u][1]));
#pragma unroll
            for (int u = 0; u < 4; u++) {
                p[u] += __shfl_xor(p[u], 1);
                p[u] += __shfl_xor(p[u], 2);
                p[u] += __shfl_xor(p[u], 4);
            }
#pragma unroll
            for (int u = 0; u < 4; u++) {
                float w = __expf(fminf(p[u] * 0.25f, 60.0f));
                acc0 += w * (bflo(vu[u]) + bfu(ee[u][0]));
                acc1 += w * (bfhi(vu[u]) + bfu(ee[u][1]));
                sw += w;
            }
        }
        for (; r < cnt; ++r) {
            int s = __shfl(sv, r);
            ushort2v ee = *(const ushort2v*)&elds[wave][r][2 * lane];
            unsigned int ku = k32[(size_t)s * 64 + lane];
            unsigned int vu = v32[(size_t)s * 64 + lane];
            float e0 = bfu(ee[0]), e1 = bfu(ee[1]);
            float part = qq.x * (bflo(ku) + e0) + qq.y * (bfhi(ku) + e1);
            part += __shfl_xor(part, 1);
            part += __shfl_xor(part, 2);
            part += __shfl_xor(part, 4);
            float w = __expf(fminf(part * 0.25f, 60.0f));
            acc0 += w * (bflo(vu) + e0);
            acc1 += w * (bfhi(vu) + e1);
            sw += w;
        }
        a0 = na0; a1 = na1; sv = nsv;
    }
    float inv = 1.0f / (sw + 1e-16f);
    float2 o;
    o.x = acc0 * inv + sk.x;
    o.y = acc1 * inv + sk.y;
    h2[(size_t)n * 64 + lane] = o;
}

// ---------------- BatchNorm stats + finalize ----------------
__global__ __launch_bounds__(128) void bn_stats_kernel(const float* __restrict__ h, int N,
                                                       float* __restrict__ sums) {
    int f = threadIdx.x;
    float s = 0.f, s2 = 0.f;
    for (int n = blockIdx.x; n < N; n += gridDim.x) {
        float x = h[(size_t)n * 128 + f];
        s += x;
        s2 += x * x;
    }
    atomicAdd(&sums[f], s);
    atomicAdd(&sums[128 + f], s2);
}

__global__ __launch_bounds__(128) void bn_finalize_kernel(
    const float* __restrict__ sums, const float* __restrict__ g,
    const float* __restrict__ be, int N,
    float* __restrict__ scale, float* __restrict__ shift)
{
    int f = threadIdx.x;
    float invN = 1.0f / (float)N;
    float mu = sums[f] * invN;
    float var = sums[128 + f] * invN - mu * mu;
    float sc = g[f] * rsqrtf(var + 1e-5f);
    scale[f] = sc;
    shift[f] = be[f] - mu * sc;
}

// ---------------------------------------------------------------------------
extern "C" void kernel_launch(void* const* d_in, const int* in_sizes, int n_in,
                              void* d_out, int out_size, void* d_ws, size_t ws_size,
                              hipStream_t stream)
{
    const float* x = (const float*)d_in[0];
    const int* edge_index = (const int*)d_in[1];
    const float* edge_attr = (const float*)d_in[2];
    int N = in_sizes[0] / 64;
    int E = in_sizes[1] / 2;
    const int* src = edge_index;
    const int* dst = edge_index + E;

    const float* W[3][9];
    for (int l = 0; l < 3; l++)
        for (int i = 0; i < 9; i++) W[l][i] = (const float*)d_in[3 + l * 9 + i];
    // 0:Wq 1:bq 2:Wk 3:bk 4:Wv 5:bv 6:We 7:Ws 8:bs
    const float* g0 = (const float*)d_in[30];
    const float* be0 = (const float*)d_in[31];
    const float* g1 = (const float*)d_in[32];
    const float* be1 = (const float*)d_in[33];

    char* p = (char*)d_ws;
    auto alloc = [&](size_t bytes) -> char* {
        char* r = p;
        p += (bytes + 255) & ~(size_t)255;
        return r;
    };
    float* q = (float*)alloc((size_t)N * 128 * 4);
    ushort_t* k = (ushort_t*)alloc((size_t)N * 128 * 2);
    ushort_t* v = (ushort_t*)alloc((size_t)N * 128 * 2);
    float* B = (float*)alloc((size_t)N * 128 * 4);
    ushort_t* ea = (ushort_t*)alloc((size_t)E * 64 * 2);
    int* row_ptr = (int*)alloc((size_t)(N + 1) * 4);
    int* cursor = (int*)alloc((size_t)N * 4);
    int* histb = (int*)alloc((size_t)N * 4);
    int* eid = (int*)alloc((size_t)E * 4);
    int* srcs = (int*)alloc((size_t)E * 4);
    int* bsums = (int*)alloc(64 * 4);
    float* sums = (float*)alloc(512 * 4);     // 2 layers x 256
    float* bnp = (float*)alloc(512 * 4);      // scale0|shift0|scale1|shift1
    ushort_t* BpackE = (ushort_t*)alloc((size_t)3 * 8192 * 2);
    ushort_t* BpackN = (ushort_t*)alloc((size_t)3 * 65536 * 2);
    float* biasc = (float*)alloc((size_t)3 * 512 * 4);

    int nb = (N + 1023) / 1024;

    // ---- CSR build (parallel scan) ----
    hipMemsetAsync(histb, 0, (size_t)N * 4, stream);
    hipMemsetAsync(sums, 0, 512 * 4, stream);
    hist_kernel<<<(E + 255) / 256, 256, 0, stream>>>(dst, E, histb);
    scan_block_kernel<<<nb, 1024, 0, stream>>>(histb, N, row_ptr, bsums);
    scan_tops_kernel<<<1, 64, 0, stream>>>(bsums, nb);
    scan_add_kernel<<<(N + 255) / 256, 256, 0, stream>>>(bsums, N, E, row_ptr, cursor);
    scatter_kernel<<<(E + 255) / 256, 256, 0, stream>>>(src, dst, E, cursor, eid, srcs);
    permute_ea_kernel<<<(E * 8 + 255) / 256, 256, 0, stream>>>(edge_attr, eid, E, ea);

    // ---- weight packing ----
    pack_We_kernel<<<(3 * 8192 + 255) / 256, 256, 0, stream>>>(W[0][6], W[1][6], W[2][6], BpackE);
    for (int l = 0; l < 3; l++) {
        int DI = (l == 0) ? 64 : 128;
        pack_Wnode_kernel<<<(DI * 512 + 255) / 256, 256, 0, stream>>>(
            W[l][0], W[l][2], W[l][4], W[l][7], DI, BpackN + (size_t)l * 65536);
        pack_bias_kernel<<<2, 256, 0, stream>>>(W[l][1], W[l][3], W[l][5], W[l][8],
                                                biasc + (size_t)l * 512);
    }

    for (int l = 0; l < 3; l++) {
        float* skipbuf = (l == 2) ? (float*)d_out : B;
        if (l == 0)
            node_gemm_mfma_kernel<64, false><<<(N + 63) / 64, 256, 0, stream>>>(
                x, N, BpackN, biasc, nullptr, nullptr, q, k, v, skipbuf);
        else
            node_gemm_mfma_kernel<128, true><<<(N + 63) / 64, 256, 0, stream>>>(
                B, N, BpackN + (size_t)l * 65536, biasc + (size_t)l * 512,
                bnp + (size_t)(l - 1) * 256, bnp + (size_t)(l - 1) * 256 + 128,
                q, k, v, skipbuf);
        agg_fused_kernel<<<(N + 3) / 4, 256, 0, stream>>>(
            row_ptr, srcs, q, k, v, ea, BpackE + (size_t)l * 8192, skipbuf, N);
        if (l < 2) {
            bn_stats_kernel<<<256, 128, 0, stream>>>(skipbuf, N, sums + (size_t)l * 256);
            const float* gg = (l == 0) ? g0 : g1;
            const float* bb = (l == 0) ? be0 : be1;
            bn_finalize_kernel<<<1, 128, 0, stream>>>(
                sums + (size_t)l * 256, gg, bb, N,
                bnp + (size_t)l * 256, bnp + (size_t)l * 256 + 128);
        }
    }

    // ---- second output: edge_attr passthrough ----
    hipMemcpyAsync((float*)d_out + (size_t)N * 128, edge_attr, (size_t)E * 64 * 4,
                   hipMemcpyDeviceToDevice, stream);
}